// Round 1
// baseline (950.329 us; speedup 1.0000x reference)
//
#include <hip/hip_runtime.h>
#include <hip/hip_bf16.h>

#define NEG_SLOPE 0.2f

// ---------------------------------------------------------------------------
// edge_attr column sums (for mean over E rows)
__global__ __launch_bounds__(256) void ea_colsum(const float* __restrict__ ea,
                                                 float* __restrict__ sums, int E_) {
    int j = threadIdx.x & 15, rl = threadIdx.x >> 4;
    float acc = 0.f;
    for (long long r = (long long)blockIdx.x * 16 + rl; r < E_; r += (long long)gridDim.x * 16)
        acc += ea[r * 16 + j];
    __shared__ float red[256];
    red[rl * 16 + j] = acc;
    __syncthreads();
    if (threadIdx.x < 16) {
        float s = 0.f;
#pragma unroll
        for (int i = 0; i < 16; i++) s += red[i * 16 + threadIdx.x];
        atomicAdd(&sums[threadIdx.x], s);
    }
}

// ---------------------------------------------------------------------------
// V[d,h] = sum_c W_e[d,128]|(h*32+c) * att_e[h*32+c]; aes[h] = mean_ea @ V
__global__ void prep_kernel(const float* __restrict__ We1, const float* __restrict__ ate1,
                            const float* __restrict__ We2, const float* __restrict__ ate2,
                            const float* __restrict__ ea_sums, float invE,
                            float* __restrict__ V1, float* __restrict__ V2,
                            float* __restrict__ aes1, float* __restrict__ aes2) {
    int tid = threadIdx.x;
    __shared__ float V1s[64], V2s[64];
    if (tid < 64) {
        int dd = tid >> 2, h = tid & 3;
        float s = 0.f;
        for (int c = 0; c < 32; c++) s += We1[dd * 128 + h * 32 + c] * ate1[h * 32 + c];
        V1[dd * 4 + h] = s; V1s[dd * 4 + h] = s;
    } else if (tid < 128) {
        int t = tid - 64, dd = t >> 2, h = t & 3;
        float s = 0.f;
        for (int c = 0; c < 32; c++) s += We2[dd * 128 + h * 32 + c] * ate2[h * 32 + c];
        V2[dd * 4 + h] = s; V2s[dd * 4 + h] = s;
    }
    __syncthreads();
    if (tid < 4) {
        float s = 0.f;
        for (int dd = 0; dd < 16; dd++) s += ea_sums[dd] * invE * V1s[dd * 4 + tid];
        aes1[tid] = s;
    } else if (tid >= 64 && tid < 68) {
        int h = tid - 64;
        float s = 0.f;
        for (int dd = 0; dd < 16; dd++) s += ea_sums[dd] * invE * V2s[dd * 4 + h];
        aes2[h] = s;
    }
}

// ---------------------------------------------------------------------------
// CSR build
__global__ void deg_kernel(const int* __restrict__ dst, int* __restrict__ deg, int E_, int n) {
    int e = blockIdx.x * blockDim.x + threadIdx.x;
    if (e >= E_ + n) return;
    int d = (e < E_) ? dst[e] : e - E_;
    atomicAdd(&deg[d], 1);
}

__global__ __launch_bounds__(1024) void scan_kernel(const int* __restrict__ deg,
                                                    int* __restrict__ rowptr,
                                                    int* __restrict__ cursor, int n) {
    __shared__ int part[1024];
    int tid = threadIdx.x;
    int chunk = (n + 1023) / 1024;
    int base = tid * chunk;
    int hi = min(base + chunk, n);
    int s = 0;
    for (int i = base; i < hi; i++) s += deg[i];
    part[tid] = s;
    __syncthreads();
    for (int off = 1; off < 1024; off <<= 1) {
        int v = (tid >= off) ? part[tid - off] : 0;
        __syncthreads();
        part[tid] += v;
        __syncthreads();
    }
    int prefix = (tid == 0) ? 0 : part[tid - 1];
    for (int i = base; i < hi; i++) {
        rowptr[i] = prefix; cursor[i] = prefix; prefix += deg[i];
    }
    if (tid == 1023) rowptr[n] = part[1023];
}

__global__ void scatter_kernel(const int* __restrict__ src, const int* __restrict__ dst,
                               int* __restrict__ cursor, int* __restrict__ csr_src,
                               int* __restrict__ slot, int E_, int n) {
    int e = blockIdx.x * blockDim.x + threadIdx.x;
    if (e >= E_ + n) return;
    int s, d;
    if (e < E_) { s = src[e]; d = dst[e]; } else { s = d = e - E_; }
    int i = atomicAdd(&cursor[d], 1);
    csr_src[i] = s;
    slot[e] = i;
}

// ---------------------------------------------------------------------------
// xw = X @ W  (128x128), plus per-head attention dots a_src/a_dst
__global__ __launch_bounds__(256) void gemm_att(const float* __restrict__ X,
                                                const float* __restrict__ W,
                                                const float* __restrict__ att_s,
                                                const float* __restrict__ att_d,
                                                float* __restrict__ XW,
                                                float* __restrict__ a_s,
                                                float* __restrict__ a_d, int n) {
    __shared__ float Wl[128 * 128];
    __shared__ float Xt[128][32];   // [k][row]
    int tid = threadIdx.x;
    {
        const float4* Wv = (const float4*)W;
        float4* Wlv = (float4*)Wl;
#pragma unroll
        for (int i = 0; i < 16; i++) Wlv[tid + i * 256] = Wv[tid + i * 256];
    }
    int cg = tid & 31;   // cols cg*4 .. cg*4+3
    int rg = tid >> 5;   // rows rg*4 .. rg*4+3 (of 32)
    float4 as4 = *(const float4*)(att_s + cg * 4);
    float4 ad4 = *(const float4*)(att_d + cg * 4);

    for (int half = 0; half < 2; half++) {
        int rowbase = blockIdx.x * 64 + half * 32;
        {
            int r = tid & 31, kb = (tid >> 5) * 16;
            int row = rowbase + r;
            __syncthreads();
#pragma unroll
            for (int q = 0; q < 4; q++) {
                float4 v = make_float4(0.f, 0.f, 0.f, 0.f);
                if (row < n) v = *(const float4*)(X + (size_t)row * 128 + kb + q * 4);
                Xt[kb + q * 4 + 0][r] = v.x;
                Xt[kb + q * 4 + 1][r] = v.y;
                Xt[kb + q * 4 + 2][r] = v.z;
                Xt[kb + q * 4 + 3][r] = v.w;
            }
            __syncthreads();
        }
        float acc[4][4];
#pragma unroll
        for (int r = 0; r < 4; r++)
#pragma unroll
            for (int c = 0; c < 4; c++) acc[r][c] = 0.f;

#pragma unroll 8
        for (int k = 0; k < 128; k++) {
            float4 xv = *(const float4*)(&Xt[k][rg * 4]);
            float4 wv = *(const float4*)(&Wl[k * 128 + cg * 4]);
            acc[0][0] += xv.x * wv.x; acc[0][1] += xv.x * wv.y; acc[0][2] += xv.x * wv.z; acc[0][3] += xv.x * wv.w;
            acc[1][0] += xv.y * wv.x; acc[1][1] += xv.y * wv.y; acc[1][2] += xv.y * wv.z; acc[1][3] += xv.y * wv.w;
            acc[2][0] += xv.z * wv.x; acc[2][1] += xv.z * wv.y; acc[2][2] += xv.z * wv.z; acc[2][3] += xv.z * wv.w;
            acc[3][0] += xv.w * wv.x; acc[3][1] += xv.w * wv.y; acc[3][2] += xv.w * wv.z; acc[3][3] += xv.w * wv.w;
        }
#pragma unroll
        for (int r = 0; r < 4; r++) {
            int row = rowbase + rg * 4 + r;
            float ss = acc[r][0] * as4.x + acc[r][1] * as4.y + acc[r][2] * as4.z + acc[r][3] * as4.w;
            float sd = acc[r][0] * ad4.x + acc[r][1] * ad4.y + acc[r][2] * ad4.z + acc[r][3] * ad4.w;
            ss += __shfl_xor(ss, 1, 8); ss += __shfl_xor(ss, 2, 8); ss += __shfl_xor(ss, 4, 8);
            sd += __shfl_xor(sd, 1, 8); sd += __shfl_xor(sd, 2, 8); sd += __shfl_xor(sd, 4, 8);
            if (row < n) {
                *(float4*)(XW + (size_t)row * 128 + cg * 4) =
                    make_float4(acc[r][0], acc[r][1], acc[r][2], acc[r][3]);
                if ((cg & 7) == 0) {
                    a_s[row * 4 + (cg >> 3)] = ss;
                    a_d[row * 4 + (cg >> 3)] = sd;
                }
            }
        }
    }
}

// ---------------------------------------------------------------------------
// per-edge alpha (pre-softmax, leaky-relu'd), written in CSR order
__global__ __launch_bounds__(256) void alpha_kernel(
    const int* __restrict__ src, const int* __restrict__ dst,
    const float* __restrict__ ea, const float* __restrict__ V,
    const float* __restrict__ aes, const float* __restrict__ a_s,
    const float* __restrict__ a_d, const int* __restrict__ slot,
    float* __restrict__ csr_alpha, int E_, int n) {
    __shared__ float Vl[64];
    __shared__ float aesl[4];
    int tid = threadIdx.x;
    if (tid < 64) Vl[tid] = V[tid];
    if (tid < 4) aesl[tid] = aes[tid];
    __syncthreads();
    int e = blockIdx.x * 256 + tid;
    if (e >= E_ + n) return;
    int s, d;
    float ae[4];
    if (e < E_) {
        s = src[e]; d = dst[e];
        ae[0] = ae[1] = ae[2] = ae[3] = 0.f;
        const float4* er = (const float4*)(ea + (size_t)e * 16);
#pragma unroll
        for (int q = 0; q < 4; q++) {
            float4 v = er[q];
#pragma unroll
            for (int h = 0; h < 4; h++) {
                ae[h] += v.x * Vl[(q * 4 + 0) * 4 + h] + v.y * Vl[(q * 4 + 1) * 4 + h] +
                         v.z * Vl[(q * 4 + 2) * 4 + h] + v.w * Vl[(q * 4 + 3) * 4 + h];
            }
        }
    } else {
        s = d = e - E_;
        ae[0] = aesl[0]; ae[1] = aesl[1]; ae[2] = aesl[2]; ae[3] = aesl[3];
    }
    float4 asv = *(const float4*)(a_s + (size_t)s * 4);
    float4 adv = *(const float4*)(a_d + (size_t)d * 4);
    float o0 = asv.x + adv.x + ae[0];
    float o1 = asv.y + adv.y + ae[1];
    float o2 = asv.z + adv.z + ae[2];
    float o3 = asv.w + adv.w + ae[3];
    o0 = o0 > 0.f ? o0 : NEG_SLOPE * o0;
    o1 = o1 > 0.f ? o1 : NEG_SLOPE * o1;
    o2 = o2 > 0.f ? o2 : NEG_SLOPE * o2;
    o3 = o3 > 0.f ? o3 : NEG_SLOPE * o3;
    *(float4*)(csr_alpha + (size_t)slot[e] * 4) = make_float4(o0, o1, o2, o3);
}

// ---------------------------------------------------------------------------
// one wave per dst node: segment softmax + weighted gather, no atomics
__global__ __launch_bounds__(256) void dst_aggregate(
    const int* __restrict__ rowptr, const int* __restrict__ csr_src,
    const float* __restrict__ csr_alpha, const float* __restrict__ XW,
    float* __restrict__ OUT, int n) {
    int d = blockIdx.x * 4 + (threadIdx.x >> 6);
    if (d >= n) return;
    int lane = threadIdx.x & 63;
    int beg = rowptr[d], end = rowptr[d + 1];

    float m0 = -1e30f, m1 = -1e30f, m2 = -1e30f, m3 = -1e30f;
    for (int i = beg + lane; i < end; i += 64) {
        float4 a = *(const float4*)(csr_alpha + (size_t)i * 4);
        m0 = fmaxf(m0, a.x); m1 = fmaxf(m1, a.y); m2 = fmaxf(m2, a.z); m3 = fmaxf(m3, a.w);
    }
#pragma unroll
    for (int off = 32; off; off >>= 1) {
        m0 = fmaxf(m0, __shfl_xor(m0, off));
        m1 = fmaxf(m1, __shfl_xor(m1, off));
        m2 = fmaxf(m2, __shfl_xor(m2, off));
        m3 = fmaxf(m3, __shfl_xor(m3, off));
    }
    int hlo = lane >> 5;  // head for channel c = lane
    float mlo = (hlo == 0) ? m0 : m1;
    float mhi = (hlo == 0) ? m2 : m3;
    float acc_lo = 0.f, acc_hi = 0.f, den_lo = 0.f, den_hi = 0.f;
    for (int i = beg; i < end; i++) {
        int s_node = csr_src[i];
        float alo = csr_alpha[(size_t)i * 4 + hlo];
        float ahi = csr_alpha[(size_t)i * 4 + 2 + hlo];
        float plo = __expf(alo - mlo);
        float phi = __expf(ahi - mhi);
        den_lo += plo; den_hi += phi;
        acc_lo += plo * XW[(size_t)s_node * 128 + lane];
        acc_hi += phi * XW[(size_t)s_node * 128 + 64 + lane];
    }
    OUT[(size_t)d * 128 + lane]      = acc_lo / (den_lo + 1e-16f);
    OUT[(size_t)d * 128 + 64 + lane] = acc_hi / (den_hi + 1e-16f);
}

// ---------------------------------------------------------------------------
__global__ void bias_relu(float* __restrict__ B, const float* __restrict__ b, int total) {
    int i = blockIdx.x * blockDim.x + threadIdx.x;
    if (i < total) {
        float v = B[i] + b[i & 127];
        B[i] = v > 0.f ? v : 0.f;
    }
}

// head-mean + bias + atomic pooling
__global__ void headmean_pool(const float* __restrict__ B, const float* __restrict__ b2,
                              const int* __restrict__ batch, float* __restrict__ pooled,
                              float* __restrict__ cnt, int n) {
    int i = blockIdx.x * blockDim.x + threadIdx.x;
    if (i >= n * 32) return;
    int node = i >> 5, c = i & 31;
    const float* r = B + (size_t)node * 128;
    float v = 0.25f * (r[c] + r[c + 32] + r[c + 64] + r[c + 96]) + b2[c];
    int g = batch[node];
    atomicAdd(&pooled[g * 32 + c], v);
    if (c == 0) atomicAdd(&cnt[g], 1.0f);
}

__global__ void mlp_kernel(const float* __restrict__ pooled, const float* __restrict__ cnt,
                           const float* __restrict__ W3, const float* __restrict__ b3,
                           const float* __restrict__ W4, const float* __restrict__ b4,
                           float* __restrict__ out) {
    int g = blockIdx.x;
    int c = threadIdx.x;
    __shared__ float t[32];
    float inv = 1.0f / fmaxf(cnt[g], 1.0f);
    if (c < 32) {
        float s = b3[c];
        for (int k = 0; k < 32; k++) s += pooled[g * 32 + k] * inv * W3[k * 32 + c];
        t[c] = fmaxf(s, 0.f);
    }
    __syncthreads();
    if (c < 2) {
        float o = b4[c];
        for (int k = 0; k < 32; k++) o += t[k] * W4[k * 2 + c];
        out[g * 2 + c] = o;
    }
}

// ---------------------------------------------------------------------------
extern "C" void kernel_launch(void* const* d_in, const int* in_sizes, int n_in,
                              void* d_out, int out_size, void* d_ws, size_t ws_size,
                              hipStream_t stream) {
    const float* x    = (const float*)d_in[0];
    const int*   eidx = (const int*)d_in[1];
    const float* ea   = (const float*)d_in[2];
    const int*   batch= (const int*)d_in[3];
    const float* W1   = (const float*)d_in[4];
    const float* as1  = (const float*)d_in[5];
    const float* ad1  = (const float*)d_in[6];
    const float* We1  = (const float*)d_in[7];
    const float* ate1 = (const float*)d_in[8];
    const float* b1   = (const float*)d_in[9];
    const float* W2   = (const float*)d_in[10];
    const float* as2  = (const float*)d_in[11];
    const float* ad2  = (const float*)d_in[12];
    const float* We2  = (const float*)d_in[13];
    const float* ate2 = (const float*)d_in[14];
    const float* b2   = (const float*)d_in[15];
    const float* W3   = (const float*)d_in[16];
    const float* b3   = (const float*)d_in[17];
    const float* W4   = (const float*)d_in[18];
    const float* b4   = (const float*)d_in[19];

    const int N_ = in_sizes[0] / 128;
    const int E_ = in_sizes[1] / 2;
    const int EN = E_ + N_;
    const int* srcp = eidx;
    const int* dstp = eidx + E_;

    char* w = (char*)d_ws;
    size_t off = 0;
    auto alloc = [&](size_t bytes) -> void* {
        void* p = w + off;
        off = (off + bytes + 255) & ~(size_t)255;
        return p;
    };
    float* A         = (float*)alloc((size_t)N_ * 128 * 4);
    float* Bb        = (float*)alloc((size_t)N_ * 128 * 4);
    float* csr_alpha = (float*)alloc((size_t)EN * 16);
    int*   csr_src   = (int*)alloc((size_t)EN * 4);
    int*   slot      = (int*)alloc((size_t)EN * 4);
    int*   rowptr    = (int*)alloc((size_t)(N_ + 1) * 4);
    int*   cursor    = (int*)alloc((size_t)N_ * 4);
    int*   deg       = (int*)alloc((size_t)N_ * 4);
    float* a_s       = (float*)alloc((size_t)N_ * 16);
    float* a_d       = (float*)alloc((size_t)N_ * 16);
    float* ea_sums   = (float*)alloc(64);
    float* V1        = (float*)alloc(256);
    float* V2        = (float*)alloc(256);
    float* aes1      = (float*)alloc(16);
    float* aes2      = (float*)alloc(16);
    float* pooled    = (float*)alloc(64 * 32 * 4);
    float* cnt       = (float*)alloc(64 * 4);

    hipMemsetAsync(deg, 0, (size_t)N_ * 4, stream);
    hipMemsetAsync(ea_sums, 0, 64, stream);
    hipMemsetAsync(pooled, 0, 64 * 32 * 4, stream);
    hipMemsetAsync(cnt, 0, 64 * 4, stream);

    int ebk = (EN + 255) / 256;

    ea_colsum<<<1024, 256, 0, stream>>>(ea, ea_sums, E_);
    deg_kernel<<<ebk, 256, 0, stream>>>(dstp, deg, E_, N_);
    scan_kernel<<<1, 1024, 0, stream>>>(deg, rowptr, cursor, N_);
    scatter_kernel<<<ebk, 256, 0, stream>>>(srcp, dstp, cursor, csr_src, slot, E_, N_);
    prep_kernel<<<1, 128, 0, stream>>>(We1, ate1, We2, ate2, ea_sums, 1.0f / (float)E_,
                                       V1, V2, aes1, aes2);

    // ---- layer 1 ----
    gemm_att<<<(N_ + 63) / 64, 256, 0, stream>>>(x, W1, as1, ad1, A, a_s, a_d, N_);
    alpha_kernel<<<ebk, 256, 0, stream>>>(srcp, dstp, ea, V1, aes1, a_s, a_d, slot,
                                          csr_alpha, E_, N_);
    dst_aggregate<<<(N_ + 3) / 4, 256, 0, stream>>>(rowptr, csr_src, csr_alpha, A, Bb, N_);
    bias_relu<<<(N_ * 128 + 255) / 256, 256, 0, stream>>>(Bb, b1, N_ * 128);

    // ---- layer 2 ----
    gemm_att<<<(N_ + 63) / 64, 256, 0, stream>>>(Bb, W2, as2, ad2, A, a_s, a_d, N_);
    alpha_kernel<<<ebk, 256, 0, stream>>>(srcp, dstp, ea, V2, aes2, a_s, a_d, slot,
                                          csr_alpha, E_, N_);
    dst_aggregate<<<(N_ + 3) / 4, 256, 0, stream>>>(rowptr, csr_src, csr_alpha, A, Bb, N_);
    headmean_pool<<<(N_ * 32 + 255) / 256, 256, 0, stream>>>(Bb, b2, batch, pooled, cnt, N_);

    // ---- graph MLP ----
    mlp_kernel<<<64, 64, 0, stream>>>(pooled, cnt, W3, b3, W4, b4, (float*)d_out);
}

// Round 2
// 578.879 us; speedup vs baseline: 1.6417x; 1.6417x over previous
//
#include <hip/hip_runtime.h>
#include <hip/hip_bf16.h>

#define NEG_SLOPE 0.2f

// ---------------------------------------------------------------------------
// edge_attr column sums (for mean over E rows)
__global__ __launch_bounds__(256) void ea_colsum(const float* __restrict__ ea,
                                                 float* __restrict__ sums, int E_) {
    int j = threadIdx.x & 15, rl = threadIdx.x >> 4;
    float acc = 0.f;
    for (long long r = (long long)blockIdx.x * 16 + rl; r < E_; r += (long long)gridDim.x * 16)
        acc += ea[r * 16 + j];
    __shared__ float red[256];
    red[rl * 16 + j] = acc;
    __syncthreads();
    if (threadIdx.x < 16) {
        float s = 0.f;
#pragma unroll
        for (int i = 0; i < 16; i++) s += red[i * 16 + threadIdx.x];
        atomicAdd(&sums[threadIdx.x], s);
    }
}

// ---------------------------------------------------------------------------
// V[d,h] = sum_c W_e[d,128]|(h*32+c) * att_e[h*32+c]; aes[h] = mean_ea @ V
__global__ void prep_kernel(const float* __restrict__ We1, const float* __restrict__ ate1,
                            const float* __restrict__ We2, const float* __restrict__ ate2,
                            const float* __restrict__ ea_sums, float invE,
                            float* __restrict__ V1, float* __restrict__ V2,
                            float* __restrict__ aes1, float* __restrict__ aes2) {
    int tid = threadIdx.x;
    __shared__ float V1s[64], V2s[64];
    if (tid < 64) {
        int dd = tid >> 2, h = tid & 3;
        float s = 0.f;
        for (int c = 0; c < 32; c++) s += We1[dd * 128 + h * 32 + c] * ate1[h * 32 + c];
        V1[dd * 4 + h] = s; V1s[dd * 4 + h] = s;
    } else if (tid < 128) {
        int t = tid - 64, dd = t >> 2, h = t & 3;
        float s = 0.f;
        for (int c = 0; c < 32; c++) s += We2[dd * 128 + h * 32 + c] * ate2[h * 32 + c];
        V2[dd * 4 + h] = s; V2s[dd * 4 + h] = s;
    }
    __syncthreads();
    if (tid < 4) {
        float s = 0.f;
        for (int dd = 0; dd < 16; dd++) s += ea_sums[dd] * invE * V1s[dd * 4 + tid];
        aes1[tid] = s;
    } else if (tid >= 64 && tid < 68) {
        int h = tid - 64;
        float s = 0.f;
        for (int dd = 0; dd < 16; dd++) s += ea_sums[dd] * invE * V2s[dd * 4 + h];
        aes2[h] = s;
    }
}

// ---------------------------------------------------------------------------
// CSR build
__global__ void deg_kernel(const int* __restrict__ dst, int* __restrict__ deg, int E_, int n) {
    int e = blockIdx.x * blockDim.x + threadIdx.x;
    if (e >= E_ + n) return;
    int d = (e < E_) ? dst[e] : e - E_;
    atomicAdd(&deg[d], 1);
}

__global__ __launch_bounds__(1024) void scan_kernel(const int* __restrict__ deg,
                                                    int* __restrict__ rowptr,
                                                    int* __restrict__ cursor, int n) {
    __shared__ int part[1024];
    int tid = threadIdx.x;
    int chunk = (n + 1023) / 1024;
    int base = tid * chunk;
    int hi = min(base + chunk, n);
    int s = 0;
    for (int i = base; i < hi; i++) s += deg[i];
    part[tid] = s;
    __syncthreads();
    for (int off = 1; off < 1024; off <<= 1) {
        int v = (tid >= off) ? part[tid - off] : 0;
        __syncthreads();
        part[tid] += v;
        __syncthreads();
    }
    int prefix = (tid == 0) ? 0 : part[tid - 1];
    for (int i = base; i < hi; i++) {
        rowptr[i] = prefix; cursor[i] = prefix; prefix += deg[i];
    }
    if (tid == 1023) rowptr[n] = part[1023];
}

__global__ void scatter_kernel(const int* __restrict__ src, const int* __restrict__ dst,
                               int* __restrict__ cursor, int* __restrict__ csr_src,
                               int* __restrict__ slot, int E_, int n) {
    int e = blockIdx.x * blockDim.x + threadIdx.x;
    if (e >= E_ + n) return;
    int s, d;
    if (e < E_) { s = src[e]; d = dst[e]; } else { s = d = e - E_; }
    int i = atomicAdd(&cursor[d], 1);
    csr_src[i] = s;
    slot[e] = i;
}

// ---------------------------------------------------------------------------
// graph boundaries in sorted batch: gstart[g] = lower_bound(batch, g)
__global__ void bounds_kernel(const int* __restrict__ batch, int* __restrict__ gstart, int n) {
    int g = threadIdx.x;
    if (g > 64) return;
    if (g == 64) { gstart[64] = n; return; }
    int lo = 0, hi = n;
    while (lo < hi) {
        int mid = (lo + hi) >> 1;
        if (batch[mid] < g) lo = mid + 1; else hi = mid;
    }
    gstart[g] = lo;
}

// ---------------------------------------------------------------------------
// xw = X @ W  (128x128), plus per-head attention dots a_src/a_dst
__global__ __launch_bounds__(256) void gemm_att(const float* __restrict__ X,
                                                const float* __restrict__ W,
                                                const float* __restrict__ att_s,
                                                const float* __restrict__ att_d,
                                                float* __restrict__ XW,
                                                float* __restrict__ a_s,
                                                float* __restrict__ a_d, int n) {
    __shared__ float Wl[128 * 128];
    __shared__ float Xt[128][32];   // [k][row]
    int tid = threadIdx.x;
    {
        const float4* Wv = (const float4*)W;
        float4* Wlv = (float4*)Wl;
#pragma unroll
        for (int i = 0; i < 16; i++) Wlv[tid + i * 256] = Wv[tid + i * 256];
    }
    int cg = tid & 31;   // cols cg*4 .. cg*4+3
    int rg = tid >> 5;   // rows rg*4 .. rg*4+3 (of 32)
    float4 as4 = *(const float4*)(att_s + cg * 4);
    float4 ad4 = *(const float4*)(att_d + cg * 4);

    for (int half = 0; half < 2; half++) {
        int rowbase = blockIdx.x * 64 + half * 32;
        {
            int r = tid & 31, kb = (tid >> 5) * 16;
            int row = rowbase + r;
            __syncthreads();
#pragma unroll
            for (int q = 0; q < 4; q++) {
                float4 v = make_float4(0.f, 0.f, 0.f, 0.f);
                if (row < n) v = *(const float4*)(X + (size_t)row * 128 + kb + q * 4);
                Xt[kb + q * 4 + 0][r] = v.x;
                Xt[kb + q * 4 + 1][r] = v.y;
                Xt[kb + q * 4 + 2][r] = v.z;
                Xt[kb + q * 4 + 3][r] = v.w;
            }
            __syncthreads();
        }
        float acc[4][4];
#pragma unroll
        for (int r = 0; r < 4; r++)
#pragma unroll
            for (int c = 0; c < 4; c++) acc[r][c] = 0.f;

#pragma unroll 8
        for (int k = 0; k < 128; k++) {
            float4 xv = *(const float4*)(&Xt[k][rg * 4]);
            float4 wv = *(const float4*)(&Wl[k * 128 + cg * 4]);
            acc[0][0] += xv.x * wv.x; acc[0][1] += xv.x * wv.y; acc[0][2] += xv.x * wv.z; acc[0][3] += xv.x * wv.w;
            acc[1][0] += xv.y * wv.x; acc[1][1] += xv.y * wv.y; acc[1][2] += xv.y * wv.z; acc[1][3] += xv.y * wv.w;
            acc[2][0] += xv.z * wv.x; acc[2][1] += xv.z * wv.y; acc[2][2] += xv.z * wv.z; acc[2][3] += xv.z * wv.w;
            acc[3][0] += xv.w * wv.x; acc[3][1] += xv.w * wv.y; acc[3][2] += xv.w * wv.z; acc[3][3] += xv.w * wv.w;
        }
#pragma unroll
        for (int r = 0; r < 4; r++) {
            int row = rowbase + rg * 4 + r;
            float ss = acc[r][0] * as4.x + acc[r][1] * as4.y + acc[r][2] * as4.z + acc[r][3] * as4.w;
            float sd = acc[r][0] * ad4.x + acc[r][1] * ad4.y + acc[r][2] * ad4.z + acc[r][3] * ad4.w;
            ss += __shfl_xor(ss, 1, 8); ss += __shfl_xor(ss, 2, 8); ss += __shfl_xor(ss, 4, 8);
            sd += __shfl_xor(sd, 1, 8); sd += __shfl_xor(sd, 2, 8); sd += __shfl_xor(sd, 4, 8);
            if (row < n) {
                *(float4*)(XW + (size_t)row * 128 + cg * 4) =
                    make_float4(acc[r][0], acc[r][1], acc[r][2], acc[r][3]);
                if ((cg & 7) == 0) {
                    a_s[row * 4 + (cg >> 3)] = ss;
                    a_d[row * 4 + (cg >> 3)] = sd;
                }
            }
        }
    }
}

// ---------------------------------------------------------------------------
// per-edge alpha (pre-softmax, leaky-relu'd), written in CSR order
__global__ __launch_bounds__(256) void alpha_kernel(
    const int* __restrict__ src, const int* __restrict__ dst,
    const float* __restrict__ ea, const float* __restrict__ V,
    const float* __restrict__ aes, const float* __restrict__ a_s,
    const float* __restrict__ a_d, const int* __restrict__ slot,
    float* __restrict__ csr_alpha, int E_, int n) {
    __shared__ float Vl[64];
    __shared__ float aesl[4];
    int tid = threadIdx.x;
    if (tid < 64) Vl[tid] = V[tid];
    if (tid < 4) aesl[tid] = aes[tid];
    __syncthreads();
    int e = blockIdx.x * 256 + tid;
    if (e >= E_ + n) return;
    int s, d;
    float ae[4];
    if (e < E_) {
        s = src[e]; d = dst[e];
        ae[0] = ae[1] = ae[2] = ae[3] = 0.f;
        const float4* er = (const float4*)(ea + (size_t)e * 16);
#pragma unroll
        for (int q = 0; q < 4; q++) {
            float4 v = er[q];
#pragma unroll
            for (int h = 0; h < 4; h++) {
                ae[h] += v.x * Vl[(q * 4 + 0) * 4 + h] + v.y * Vl[(q * 4 + 1) * 4 + h] +
                         v.z * Vl[(q * 4 + 2) * 4 + h] + v.w * Vl[(q * 4 + 3) * 4 + h];
            }
        }
    } else {
        s = d = e - E_;
        ae[0] = aesl[0]; ae[1] = aesl[1]; ae[2] = aesl[2]; ae[3] = aesl[3];
    }
    float4 asv = *(const float4*)(a_s + (size_t)s * 4);
    float4 adv = *(const float4*)(a_d + (size_t)d * 4);
    float o0 = asv.x + adv.x + ae[0];
    float o1 = asv.y + adv.y + ae[1];
    float o2 = asv.z + adv.z + ae[2];
    float o3 = asv.w + adv.w + ae[3];
    o0 = o0 > 0.f ? o0 : NEG_SLOPE * o0;
    o1 = o1 > 0.f ? o1 : NEG_SLOPE * o1;
    o2 = o2 > 0.f ? o2 : NEG_SLOPE * o2;
    o3 = o3 > 0.f ? o3 : NEG_SLOPE * o3;
    *(float4*)(csr_alpha + (size_t)slot[e] * 4) = make_float4(o0, o1, o2, o3);
}

// ---------------------------------------------------------------------------
// one wave per dst node: segment softmax + weighted gather, no atomics
__global__ __launch_bounds__(256) void dst_aggregate(
    const int* __restrict__ rowptr, const int* __restrict__ csr_src,
    const float* __restrict__ csr_alpha, const float* __restrict__ XW,
    float* __restrict__ OUT, int n) {
    int d = blockIdx.x * 4 + (threadIdx.x >> 6);
    if (d >= n) return;
    int lane = threadIdx.x & 63;
    int beg = rowptr[d], end = rowptr[d + 1];

    float m0 = -1e30f, m1 = -1e30f, m2 = -1e30f, m3 = -1e30f;
    for (int i = beg + lane; i < end; i += 64) {
        float4 a = *(const float4*)(csr_alpha + (size_t)i * 4);
        m0 = fmaxf(m0, a.x); m1 = fmaxf(m1, a.y); m2 = fmaxf(m2, a.z); m3 = fmaxf(m3, a.w);
    }
#pragma unroll
    for (int off = 32; off; off >>= 1) {
        m0 = fmaxf(m0, __shfl_xor(m0, off));
        m1 = fmaxf(m1, __shfl_xor(m1, off));
        m2 = fmaxf(m2, __shfl_xor(m2, off));
        m3 = fmaxf(m3, __shfl_xor(m3, off));
    }
    int hlo = lane >> 5;  // head for channel c = lane
    float mlo = (hlo == 0) ? m0 : m1;
    float mhi = (hlo == 0) ? m2 : m3;
    float acc_lo = 0.f, acc_hi = 0.f, den_lo = 0.f, den_hi = 0.f;
    for (int i = beg; i < end; i++) {
        int s_node = csr_src[i];
        float alo = csr_alpha[(size_t)i * 4 + hlo];
        float ahi = csr_alpha[(size_t)i * 4 + 2 + hlo];
        float plo = __expf(alo - mlo);
        float phi = __expf(ahi - mhi);
        den_lo += plo; den_hi += phi;
        acc_lo += plo * XW[(size_t)s_node * 128 + lane];
        acc_hi += phi * XW[(size_t)s_node * 128 + 64 + lane];
    }
    OUT[(size_t)d * 128 + lane]      = acc_lo / (den_lo + 1e-16f);
    OUT[(size_t)d * 128 + 64 + lane] = acc_hi / (den_hi + 1e-16f);
}

// ---------------------------------------------------------------------------
__global__ void bias_relu(float* __restrict__ B, const float* __restrict__ b, int total4) {
    int i = blockIdx.x * blockDim.x + threadIdx.x;
    if (i >= total4) return;
    float4 v = ((const float4*)B)[i];
    const float4 bb = ((const float4*)b)[i & 31];
    v.x = fmaxf(v.x + bb.x, 0.f);
    v.y = fmaxf(v.y + bb.y, 0.f);
    v.z = fmaxf(v.z + bb.z, 0.f);
    v.w = fmaxf(v.w + bb.w, 0.f);
    ((float4*)B)[i] = v;
}

// ---------------------------------------------------------------------------
// pooled[g,c] = sum over nodes of graph g of head-mean; one block per (g,split)
#define POOL_SPLITS 8
__global__ __launch_bounds__(256) void pool_kernel(const float* __restrict__ B,
                                                   const int* __restrict__ gstart,
                                                   float* __restrict__ pooled) {
    int g = blockIdx.x / POOL_SPLITS, sp = blockIdx.x % POOL_SPLITS;
    int lo = gstart[g], hi = gstart[g + 1];
    int cnt = hi - lo;
    int per = (cnt + POOL_SPLITS - 1) / POOL_SPLITS;
    int s0 = lo + sp * per;
    int s1 = min(s0 + per, hi);
    int c = threadIdx.x & 31, rl = threadIdx.x >> 5;
    float acc = 0.f;
    for (int node = s0 + rl; node < s1; node += 8) {
        const float* r = B + (size_t)node * 128;
        acc += 0.25f * (r[c] + r[c + 32] + r[c + 64] + r[c + 96]);
    }
    __shared__ float red[8][32];
    red[rl][c] = acc;
    __syncthreads();
    if (threadIdx.x < 32) {
        float s = 0.f;
#pragma unroll
        for (int i = 0; i < 8; i++) s += red[i][threadIdx.x];
        atomicAdd(&pooled[g * 32 + threadIdx.x], s);
    }
}

__global__ void mlp_kernel(const float* __restrict__ pooled, const int* __restrict__ gstart,
                           const float* __restrict__ b2,
                           const float* __restrict__ W3, const float* __restrict__ b3,
                           const float* __restrict__ W4, const float* __restrict__ b4,
                           float* __restrict__ out) {
    int g = blockIdx.x;
    int c = threadIdx.x;
    __shared__ float pm[32];
    __shared__ float t[32];
    int cnt = gstart[g + 1] - gstart[g];
    if (c < 32) {
        float m = 0.f;
        if (cnt > 0) m = pooled[g * 32 + c] / (float)cnt + b2[c];
        pm[c] = m;
    }
    __syncthreads();
    if (c < 32) {
        float s = b3[c];
        for (int k = 0; k < 32; k++) s += pm[k] * W3[k * 32 + c];
        t[c] = fmaxf(s, 0.f);
    }
    __syncthreads();
    if (c < 2) {
        float o = b4[c];
        for (int k = 0; k < 32; k++) o += t[k] * W4[k * 2 + c];
        out[g * 2 + c] = o;
    }
}

// ---------------------------------------------------------------------------
extern "C" void kernel_launch(void* const* d_in, const int* in_sizes, int n_in,
                              void* d_out, int out_size, void* d_ws, size_t ws_size,
                              hipStream_t stream) {
    const float* x    = (const float*)d_in[0];
    const int*   eidx = (const int*)d_in[1];
    const float* ea   = (const float*)d_in[2];
    const int*   batch= (const int*)d_in[3];
    const float* W1   = (const float*)d_in[4];
    const float* as1  = (const float*)d_in[5];
    const float* ad1  = (const float*)d_in[6];
    const float* We1  = (const float*)d_in[7];
    const float* ate1 = (const float*)d_in[8];
    const float* b1   = (const float*)d_in[9];
    const float* W2   = (const float*)d_in[10];
    const float* as2  = (const float*)d_in[11];
    const float* ad2  = (const float*)d_in[12];
    const float* We2  = (const float*)d_in[13];
    const float* ate2 = (const float*)d_in[14];
    const float* b2   = (const float*)d_in[15];
    const float* W3   = (const float*)d_in[16];
    const float* b3   = (const float*)d_in[17];
    const float* W4   = (const float*)d_in[18];
    const float* b4   = (const float*)d_in[19];

    const int N_ = in_sizes[0] / 128;
    const int E_ = in_sizes[1] / 2;
    const int EN = E_ + N_;
    const int* srcp = eidx;
    const int* dstp = eidx + E_;

    char* w = (char*)d_ws;
    size_t off = 0;
    auto alloc = [&](size_t bytes) -> void* {
        void* p = w + off;
        off = (off + bytes + 255) & ~(size_t)255;
        return p;
    };
    float* A         = (float*)alloc((size_t)N_ * 128 * 4);
    float* Bb        = (float*)alloc((size_t)N_ * 128 * 4);
    float* csr_alpha = (float*)alloc((size_t)EN * 16);
    int*   csr_src   = (int*)alloc((size_t)EN * 4);
    int*   slot      = (int*)alloc((size_t)EN * 4);
    int*   rowptr    = (int*)alloc((size_t)(N_ + 1) * 4);
    int*   cursor    = (int*)alloc((size_t)N_ * 4);
    int*   deg       = (int*)alloc((size_t)N_ * 4);
    float* a_s       = (float*)alloc((size_t)N_ * 16);
    float* a_d       = (float*)alloc((size_t)N_ * 16);
    float* ea_sums   = (float*)alloc(64);
    float* V1        = (float*)alloc(256);
    float* V2        = (float*)alloc(256);
    float* aes1      = (float*)alloc(16);
    float* aes2      = (float*)alloc(16);
    float* pooled    = (float*)alloc(64 * 32 * 4);
    int*   gstart    = (int*)alloc(65 * 4);

    hipMemsetAsync(deg, 0, (size_t)N_ * 4, stream);
    hipMemsetAsync(ea_sums, 0, 64, stream);
    hipMemsetAsync(pooled, 0, 64 * 32 * 4, stream);

    int ebk = (EN + 255) / 256;

    ea_colsum<<<1024, 256, 0, stream>>>(ea, ea_sums, E_);
    deg_kernel<<<ebk, 256, 0, stream>>>(dstp, deg, E_, N_);
    scan_kernel<<<1, 1024, 0, stream>>>(deg, rowptr, cursor, N_);
    scatter_kernel<<<ebk, 256, 0, stream>>>(srcp, dstp, cursor, csr_src, slot, E_, N_);
    prep_kernel<<<1, 128, 0, stream>>>(We1, ate1, We2, ate2, ea_sums, 1.0f / (float)E_,
                                       V1, V2, aes1, aes2);
    bounds_kernel<<<1, 128, 0, stream>>>(batch, gstart, N_);

    // ---- layer 1 ----
    gemm_att<<<(N_ + 63) / 64, 256, 0, stream>>>(x, W1, as1, ad1, A, a_s, a_d, N_);
    alpha_kernel<<<ebk, 256, 0, stream>>>(srcp, dstp, ea, V1, aes1, a_s, a_d, slot,
                                          csr_alpha, E_, N_);
    dst_aggregate<<<(N_ + 3) / 4, 256, 0, stream>>>(rowptr, csr_src, csr_alpha, A, Bb, N_);
    bias_relu<<<(N_ * 32 + 255) / 256, 256, 0, stream>>>(Bb, b1, N_ * 32);

    // ---- layer 2 ----
    gemm_att<<<(N_ + 63) / 64, 256, 0, stream>>>(Bb, W2, as2, ad2, A, a_s, a_d, N_);
    alpha_kernel<<<ebk, 256, 0, stream>>>(srcp, dstp, ea, V2, aes2, a_s, a_d, slot,
                                          csr_alpha, E_, N_);
    dst_aggregate<<<(N_ + 3) / 4, 256, 0, stream>>>(rowptr, csr_src, csr_alpha, A, Bb, N_);
    pool_kernel<<<64 * POOL_SPLITS, 256, 0, stream>>>(Bb, gstart, pooled);

    // ---- graph MLP ----
    mlp_kernel<<<64, 64, 0, stream>>>(pooled, gstart, b2, W3, b3, W4, b4, (float*)d_out);
}

// Round 3
// 481.270 us; speedup vs baseline: 1.9746x; 1.2028x over previous
//
#include <hip/hip_runtime.h>
#include <hip/hip_bf16.h>

#define NEG_SLOPE 0.2f

// ---------------------------------------------------------------------------
// edge_attr column sums (for mean over E rows)
__global__ __launch_bounds__(256) void ea_colsum(const float* __restrict__ ea,
                                                 float* __restrict__ sums, int E_) {
    int j = threadIdx.x & 15, rl = threadIdx.x >> 4;
    float acc = 0.f;
    for (long long r = (long long)blockIdx.x * 16 + rl; r < E_; r += (long long)gridDim.x * 16)
        acc += ea[r * 16 + j];
    __shared__ float red[256];
    red[rl * 16 + j] = acc;
    __syncthreads();
    if (threadIdx.x < 16) {
        float s = 0.f;
#pragma unroll
        for (int i = 0; i < 16; i++) s += red[i * 16 + threadIdx.x];
        atomicAdd(&sums[threadIdx.x], s);
    }
}

// ---------------------------------------------------------------------------
// V[d,h] = sum_c W_e[d,128]|(h*32+c) * att_e[h*32+c]; aes[h] = mean_ea @ V
__global__ void prep_kernel(const float* __restrict__ We1, const float* __restrict__ ate1,
                            const float* __restrict__ We2, const float* __restrict__ ate2,
                            const float* __restrict__ ea_sums, float invE,
                            float* __restrict__ V1, float* __restrict__ V2,
                            float* __restrict__ aes1, float* __restrict__ aes2) {
    int tid = threadIdx.x;
    __shared__ float V1s[64], V2s[64];
    if (tid < 64) {
        int dd = tid >> 2, h = tid & 3;
        float s = 0.f;
        for (int c = 0; c < 32; c++) s += We1[dd * 128 + h * 32 + c] * ate1[h * 32 + c];
        V1[dd * 4 + h] = s; V1s[dd * 4 + h] = s;
    } else if (tid < 128) {
        int t = tid - 64, dd = t >> 2, h = t & 3;
        float s = 0.f;
        for (int c = 0; c < 32; c++) s += We2[dd * 128 + h * 32 + c] * ate2[h * 32 + c];
        V2[dd * 4 + h] = s; V2s[dd * 4 + h] = s;
    }
    __syncthreads();
    if (tid < 4) {
        float s = 0.f;
        for (int dd = 0; dd < 16; dd++) s += ea_sums[dd] * invE * V1s[dd * 4 + tid];
        aes1[tid] = s;
    } else if (tid >= 64 && tid < 68) {
        int h = tid - 64;
        float s = 0.f;
        for (int dd = 0; dd < 16; dd++) s += ea_sums[dd] * invE * V2s[dd * 4 + h];
        aes2[h] = s;
    }
}

// ---------------------------------------------------------------------------
// CSR build
__global__ void deg_kernel(const int* __restrict__ dst, int* __restrict__ deg, int E_, int n) {
    int e = blockIdx.x * blockDim.x + threadIdx.x;
    if (e >= E_ + n) return;
    int d = (e < E_) ? dst[e] : e - E_;
    atomicAdd(&deg[d], 1);
}

// ---- 3-phase parallel exclusive scan over deg[0..n) -> rowptr, cursor ----
#define SCAN_PER 8
#define SCAN_CHUNK 2048  // 256 threads * 8

__global__ __launch_bounds__(256) void scan_part(const int* __restrict__ deg,
                                                 int* __restrict__ rowptr,
                                                 int* __restrict__ blocksum, int n) {
    int tid = threadIdx.x;
    int base = blockIdx.x * SCAN_CHUNK + tid * SCAN_PER;
    int v[SCAN_PER];
    int s = 0;
#pragma unroll
    for (int k = 0; k < SCAN_PER; k++) {
        int i = base + k;
        int d = (i < n) ? deg[i] : 0;
        v[k] = s;
        s += d;
    }
    __shared__ int part[256];
    part[tid] = s;
    __syncthreads();
    for (int off = 1; off < 256; off <<= 1) {
        int t = (tid >= off) ? part[tid - off] : 0;
        __syncthreads();
        part[tid] += t;
        __syncthreads();
    }
    int prefix = (tid == 0) ? 0 : part[tid - 1];
#pragma unroll
    for (int k = 0; k < SCAN_PER; k++) {
        int i = base + k;
        if (i < n) rowptr[i] = prefix + v[k];
    }
    if (tid == 255) blocksum[blockIdx.x] = part[255];
}

__global__ void scan_mid(int* __restrict__ blocksum, int nb) {
    if (threadIdx.x == 0) {
        int acc = 0;
        for (int b = 0; b < nb; b++) { int t = blocksum[b]; blocksum[b] = acc; acc += t; }
    }
}

__global__ __launch_bounds__(256) void scan_add(int* __restrict__ rowptr,
                                                int* __restrict__ cursor,
                                                const int* __restrict__ blocksum,
                                                int n, int total) {
    int base = blockIdx.x * SCAN_CHUNK + threadIdx.x * SCAN_PER;
    int off = blocksum[blockIdx.x];
#pragma unroll
    for (int k = 0; k < SCAN_PER; k++) {
        int j = base + k;
        if (j < n) { int r = rowptr[j] + off; rowptr[j] = r; cursor[j] = r; }
    }
    if (blockIdx.x == 0 && threadIdx.x == 0) rowptr[n] = total;
}

__global__ void scatter_kernel(const int* __restrict__ src, const int* __restrict__ dst,
                               int* __restrict__ cursor, int* __restrict__ csr_src,
                               int* __restrict__ slot, int E_, int n) {
    int e = blockIdx.x * blockDim.x + threadIdx.x;
    if (e >= E_ + n) return;
    int s, d;
    if (e < E_) { s = src[e]; d = dst[e]; } else { s = d = e - E_; }
    int i = atomicAdd(&cursor[d], 1);
    csr_src[i] = s;
    slot[e] = i;
}

// ---------------------------------------------------------------------------
// graph boundaries in sorted batch: gstart[g] = lower_bound(batch, g)
__global__ void bounds_kernel(const int* __restrict__ batch, int* __restrict__ gstart, int n) {
    int g = threadIdx.x;
    if (g > 64) return;
    if (g == 64) { gstart[64] = n; return; }
    int lo = 0, hi = n;
    while (lo < hi) {
        int mid = (lo + hi) >> 1;
        if (batch[mid] < g) lo = mid + 1; else hi = mid;
    }
    gstart[g] = lo;
}

// ---------------------------------------------------------------------------
// xw = X @ W  (128x128), plus per-head attention dots a_src/a_dst
__global__ __launch_bounds__(256) void gemm_att(const float* __restrict__ X,
                                                const float* __restrict__ W,
                                                const float* __restrict__ att_s,
                                                const float* __restrict__ att_d,
                                                float* __restrict__ XW,
                                                float* __restrict__ a_s,
                                                float* __restrict__ a_d, int n) {
    __shared__ float Wl[128 * 128];
    __shared__ float Xt[128][32];   // [k][row]
    int tid = threadIdx.x;
    {
        const float4* Wv = (const float4*)W;
        float4* Wlv = (float4*)Wl;
#pragma unroll
        for (int i = 0; i < 16; i++) Wlv[tid + i * 256] = Wv[tid + i * 256];
    }
    int cg = tid & 31;   // cols cg*4 .. cg*4+3
    int rg = tid >> 5;   // rows rg*4 .. rg*4+3 (of 32)
    float4 as4 = *(const float4*)(att_s + cg * 4);
    float4 ad4 = *(const float4*)(att_d + cg * 4);

    for (int half = 0; half < 2; half++) {
        int rowbase = blockIdx.x * 64 + half * 32;
        {
            int r = tid & 31, kb = (tid >> 5) * 16;
            int row = rowbase + r;
            __syncthreads();
#pragma unroll
            for (int q = 0; q < 4; q++) {
                float4 v = make_float4(0.f, 0.f, 0.f, 0.f);
                if (row < n) v = *(const float4*)(X + (size_t)row * 128 + kb + q * 4);
                Xt[kb + q * 4 + 0][r] = v.x;
                Xt[kb + q * 4 + 1][r] = v.y;
                Xt[kb + q * 4 + 2][r] = v.z;
                Xt[kb + q * 4 + 3][r] = v.w;
            }
            __syncthreads();
        }
        float acc[4][4];
#pragma unroll
        for (int r = 0; r < 4; r++)
#pragma unroll
            for (int c = 0; c < 4; c++) acc[r][c] = 0.f;

#pragma unroll 8
        for (int k = 0; k < 128; k++) {
            float4 xv = *(const float4*)(&Xt[k][rg * 4]);
            float4 wv = *(const float4*)(&Wl[k * 128 + cg * 4]);
            acc[0][0] += xv.x * wv.x; acc[0][1] += xv.x * wv.y; acc[0][2] += xv.x * wv.z; acc[0][3] += xv.x * wv.w;
            acc[1][0] += xv.y * wv.x; acc[1][1] += xv.y * wv.y; acc[1][2] += xv.y * wv.z; acc[1][3] += xv.y * wv.w;
            acc[2][0] += xv.z * wv.x; acc[2][1] += xv.z * wv.y; acc[2][2] += xv.z * wv.z; acc[2][3] += xv.z * wv.w;
            acc[3][0] += xv.w * wv.x; acc[3][1] += xv.w * wv.y; acc[3][2] += xv.w * wv.z; acc[3][3] += xv.w * wv.w;
        }
#pragma unroll
        for (int r = 0; r < 4; r++) {
            int row = rowbase + rg * 4 + r;
            float ss = acc[r][0] * as4.x + acc[r][1] * as4.y + acc[r][2] * as4.z + acc[r][3] * as4.w;
            float sd = acc[r][0] * ad4.x + acc[r][1] * ad4.y + acc[r][2] * ad4.z + acc[r][3] * ad4.w;
            ss += __shfl_xor(ss, 1, 8); ss += __shfl_xor(ss, 2, 8); ss += __shfl_xor(ss, 4, 8);
            sd += __shfl_xor(sd, 1, 8); sd += __shfl_xor(sd, 2, 8); sd += __shfl_xor(sd, 4, 8);
            if (row < n) {
                *(float4*)(XW + (size_t)row * 128 + cg * 4) =
                    make_float4(acc[r][0], acc[r][1], acc[r][2], acc[r][3]);
                if ((cg & 7) == 0) {
                    a_s[row * 4 + (cg >> 3)] = ss;
                    a_d[row * 4 + (cg >> 3)] = sd;
                }
            }
        }
    }
}

// ---------------------------------------------------------------------------
// per-edge alpha (pre-softmax, leaky-relu'd), written in CSR order
__global__ __launch_bounds__(256) void alpha_kernel(
    const int* __restrict__ src, const int* __restrict__ dst,
    const float* __restrict__ ea, const float* __restrict__ V,
    const float* __restrict__ aes, const float* __restrict__ a_s,
    const float* __restrict__ a_d, const int* __restrict__ slot,
    float* __restrict__ csr_alpha, int E_, int n) {
    __shared__ float Vl[64];
    __shared__ float aesl[4];
    int tid = threadIdx.x;
    if (tid < 64) Vl[tid] = V[tid];
    if (tid < 4) aesl[tid] = aes[tid];
    __syncthreads();
    int e = blockIdx.x * 256 + tid;
    if (e >= E_ + n) return;
    int s, d;
    float ae[4];
    if (e < E_) {
        s = src[e]; d = dst[e];
        ae[0] = ae[1] = ae[2] = ae[3] = 0.f;
        const float4* er = (const float4*)(ea + (size_t)e * 16);
#pragma unroll
        for (int q = 0; q < 4; q++) {
            float4 v = er[q];
#pragma unroll
            for (int h = 0; h < 4; h++) {
                ae[h] += v.x * Vl[(q * 4 + 0) * 4 + h] + v.y * Vl[(q * 4 + 1) * 4 + h] +
                         v.z * Vl[(q * 4 + 2) * 4 + h] + v.w * Vl[(q * 4 + 3) * 4 + h];
            }
        }
    } else {
        s = d = e - E_;
        ae[0] = aesl[0]; ae[1] = aesl[1]; ae[2] = aesl[2]; ae[3] = aesl[3];
    }
    float4 asv = *(const float4*)(a_s + (size_t)s * 4);
    float4 adv = *(const float4*)(a_d + (size_t)d * 4);
    float o0 = asv.x + adv.x + ae[0];
    float o1 = asv.y + adv.y + ae[1];
    float o2 = asv.z + adv.z + ae[2];
    float o3 = asv.w + adv.w + ae[3];
    o0 = o0 > 0.f ? o0 : NEG_SLOPE * o0;
    o1 = o1 > 0.f ? o1 : NEG_SLOPE * o1;
    o2 = o2 > 0.f ? o2 : NEG_SLOPE * o2;
    o3 = o3 > 0.f ? o3 : NEG_SLOPE * o3;
    *(float4*)(csr_alpha + (size_t)slot[e] * 4) = make_float4(o0, o1, o2, o3);
}

// ---------------------------------------------------------------------------
// one wave per dst node: segment softmax + weighted gather, no atomics
__global__ __launch_bounds__(256) void dst_aggregate(
    const int* __restrict__ rowptr, const int* __restrict__ csr_src,
    const float* __restrict__ csr_alpha, const float* __restrict__ XW,
    float* __restrict__ OUT, int n) {
    int d = blockIdx.x * 4 + (threadIdx.x >> 6);
    if (d >= n) return;
    int lane = threadIdx.x & 63;
    int beg = rowptr[d], end = rowptr[d + 1];

    float m0 = -1e30f, m1 = -1e30f, m2 = -1e30f, m3 = -1e30f;
    for (int i = beg + lane; i < end; i += 64) {
        float4 a = *(const float4*)(csr_alpha + (size_t)i * 4);
        m0 = fmaxf(m0, a.x); m1 = fmaxf(m1, a.y); m2 = fmaxf(m2, a.z); m3 = fmaxf(m3, a.w);
    }
#pragma unroll
    for (int off = 32; off; off >>= 1) {
        m0 = fmaxf(m0, __shfl_xor(m0, off));
        m1 = fmaxf(m1, __shfl_xor(m1, off));
        m2 = fmaxf(m2, __shfl_xor(m2, off));
        m3 = fmaxf(m3, __shfl_xor(m3, off));
    }
    int hlo = lane >> 5;  // head for channel c = lane
    float mlo = (hlo == 0) ? m0 : m1;
    float mhi = (hlo == 0) ? m2 : m3;
    float acc_lo = 0.f, acc_hi = 0.f, den_lo = 0.f, den_hi = 0.f;
    for (int i = beg; i < end; i++) {
        int s_node = csr_src[i];
        float alo = csr_alpha[(size_t)i * 4 + hlo];
        float ahi = csr_alpha[(size_t)i * 4 + 2 + hlo];
        float plo = __expf(alo - mlo);
        float phi = __expf(ahi - mhi);
        den_lo += plo; den_hi += phi;
        acc_lo += plo * XW[(size_t)s_node * 128 + lane];
        acc_hi += phi * XW[(size_t)s_node * 128 + 64 + lane];
    }
    OUT[(size_t)d * 128 + lane]      = acc_lo / (den_lo + 1e-16f);
    OUT[(size_t)d * 128 + 64 + lane] = acc_hi / (den_hi + 1e-16f);
}

// ---------------------------------------------------------------------------
__global__ void bias_relu(float* __restrict__ B, const float* __restrict__ b, int total4) {
    int i = blockIdx.x * blockDim.x + threadIdx.x;
    if (i >= total4) return;
    float4 v = ((const float4*)B)[i];
    const float4 bb = ((const float4*)b)[i & 31];
    v.x = fmaxf(v.x + bb.x, 0.f);
    v.y = fmaxf(v.y + bb.y, 0.f);
    v.z = fmaxf(v.z + bb.z, 0.f);
    v.w = fmaxf(v.w + bb.w, 0.f);
    ((float4*)B)[i] = v;
}

// ---------------------------------------------------------------------------
// pooled[g,c] = sum over nodes of graph g of head-mean; one block per (g,split)
#define POOL_SPLITS 8
__global__ __launch_bounds__(256) void pool_kernel(const float* __restrict__ B,
                                                   const int* __restrict__ gstart,
                                                   float* __restrict__ pooled) {
    int g = blockIdx.x / POOL_SPLITS, sp = blockIdx.x % POOL_SPLITS;
    int lo = gstart[g], hi = gstart[g + 1];
    int cnt = hi - lo;
    int per = (cnt + POOL_SPLITS - 1) / POOL_SPLITS;
    int s0 = lo + sp * per;
    int s1 = min(s0 + per, hi);
    int c = threadIdx.x & 31, rl = threadIdx.x >> 5;
    float acc = 0.f;
    for (int node = s0 + rl; node < s1; node += 8) {
        const float* r = B + (size_t)node * 128;
        acc += 0.25f * (r[c] + r[c + 32] + r[c + 64] + r[c + 96]);
    }
    __shared__ float red[8][32];
    red[rl][c] = acc;
    __syncthreads();
    if (threadIdx.x < 32) {
        float s = 0.f;
#pragma unroll
        for (int i = 0; i < 8; i++) s += red[i][threadIdx.x];
        atomicAdd(&pooled[g * 32 + threadIdx.x], s);
    }
}

__global__ void mlp_kernel(const float* __restrict__ pooled, const int* __restrict__ gstart,
                           const float* __restrict__ b2,
                           const float* __restrict__ W3, const float* __restrict__ b3,
                           const float* __restrict__ W4, const float* __restrict__ b4,
                           float* __restrict__ out) {
    int g = blockIdx.x;
    int c = threadIdx.x;
    __shared__ float pm[32];
    __shared__ float t[32];
    int cnt = gstart[g + 1] - gstart[g];
    if (c < 32) {
        float m = 0.f;
        if (cnt > 0) m = pooled[g * 32 + c] / (float)cnt + b2[c];
        pm[c] = m;
    }
    __syncthreads();
    if (c < 32) {
        float s = b3[c];
        for (int k = 0; k < 32; k++) s += pm[k] * W3[k * 32 + c];
        t[c] = fmaxf(s, 0.f);
    }
    __syncthreads();
    if (c < 2) {
        float o = b4[c];
        for (int k = 0; k < 32; k++) o += t[k] * W4[k * 2 + c];
        out[g * 2 + c] = o;
    }
}

// ---------------------------------------------------------------------------
extern "C" void kernel_launch(void* const* d_in, const int* in_sizes, int n_in,
                              void* d_out, int out_size, void* d_ws, size_t ws_size,
                              hipStream_t stream) {
    const float* x    = (const float*)d_in[0];
    const int*   eidx = (const int*)d_in[1];
    const float* ea   = (const float*)d_in[2];
    const int*   batch= (const int*)d_in[3];
    const float* W1   = (const float*)d_in[4];
    const float* as1  = (const float*)d_in[5];
    const float* ad1  = (const float*)d_in[6];
    const float* We1  = (const float*)d_in[7];
    const float* ate1 = (const float*)d_in[8];
    const float* b1   = (const float*)d_in[9];
    const float* W2   = (const float*)d_in[10];
    const float* as2  = (const float*)d_in[11];
    const float* ad2  = (const float*)d_in[12];
    const float* We2  = (const float*)d_in[13];
    const float* ate2 = (const float*)d_in[14];
    const float* b2   = (const float*)d_in[15];
    const float* W3   = (const float*)d_in[16];
    const float* b3   = (const float*)d_in[17];
    const float* W4   = (const float*)d_in[18];
    const float* b4   = (const float*)d_in[19];

    const int N_ = in_sizes[0] / 128;
    const int E_ = in_sizes[1] / 2;
    const int EN = E_ + N_;
    const int* srcp = eidx;
    const int* dstp = eidx + E_;

    char* w = (char*)d_ws;
    size_t off = 0;
    auto alloc = [&](size_t bytes) -> void* {
        void* p = w + off;
        off = (off + bytes + 255) & ~(size_t)255;
        return p;
    };
    float* A         = (float*)alloc((size_t)N_ * 128 * 4);
    float* Bb        = (float*)alloc((size_t)N_ * 128 * 4);
    float* csr_alpha = (float*)alloc((size_t)EN * 16);
    int*   csr_src   = (int*)alloc((size_t)EN * 4);
    int*   slot      = (int*)alloc((size_t)EN * 4);
    int*   rowptr    = (int*)alloc((size_t)(N_ + 1) * 4);
    int*   cursor    = (int*)alloc((size_t)N_ * 4);
    int*   deg       = (int*)alloc((size_t)N_ * 4);
    int*   blocksum  = (int*)alloc(((size_t)N_ / SCAN_CHUNK + 2) * 4);
    float* a_s       = (float*)alloc((size_t)N_ * 16);
    float* a_d       = (float*)alloc((size_t)N_ * 16);
    float* ea_sums   = (float*)alloc(64);
    float* V1        = (float*)alloc(256);
    float* V2        = (float*)alloc(256);
    float* aes1      = (float*)alloc(16);
    float* aes2      = (float*)alloc(16);
    float* pooled    = (float*)alloc(64 * 32 * 4);
    int*   gstart    = (int*)alloc(65 * 4);

    hipMemsetAsync(deg, 0, (size_t)N_ * 4, stream);
    hipMemsetAsync(ea_sums, 0, 64, stream);
    hipMemsetAsync(pooled, 0, 64 * 32 * 4, stream);

    int ebk = (EN + 255) / 256;
    int nsb = (N_ + SCAN_CHUNK - 1) / SCAN_CHUNK;

    ea_colsum<<<1024, 256, 0, stream>>>(ea, ea_sums, E_);
    deg_kernel<<<ebk, 256, 0, stream>>>(dstp, deg, E_, N_);
    scan_part<<<nsb, 256, 0, stream>>>(deg, rowptr, blocksum, N_);
    scan_mid<<<1, 64, 0, stream>>>(blocksum, nsb);
    scan_add<<<nsb, 256, 0, stream>>>(rowptr, cursor, blocksum, N_, EN);
    scatter_kernel<<<ebk, 256, 0, stream>>>(srcp, dstp, cursor, csr_src, slot, E_, N_);
    prep_kernel<<<1, 128, 0, stream>>>(We1, ate1, We2, ate2, ea_sums, 1.0f / (float)E_,
                                       V1, V2, aes1, aes2);
    bounds_kernel<<<1, 128, 0, stream>>>(batch, gstart, N_);

    // ---- layer 1 ----
    gemm_att<<<(N_ + 63) / 64, 256, 0, stream>>>(x, W1, as1, ad1, A, a_s, a_d, N_);
    alpha_kernel<<<ebk, 256, 0, stream>>>(srcp, dstp, ea, V1, aes1, a_s, a_d, slot,
                                          csr_alpha, E_, N_);
    dst_aggregate<<<(N_ + 3) / 4, 256, 0, stream>>>(rowptr, csr_src, csr_alpha, A, Bb, N_);
    bias_relu<<<(N_ * 32 + 255) / 256, 256, 0, stream>>>(Bb, b1, N_ * 32);

    // ---- layer 2 ----
    gemm_att<<<(N_ + 63) / 64, 256, 0, stream>>>(Bb, W2, as2, ad2, A, a_s, a_d, N_);
    alpha_kernel<<<ebk, 256, 0, stream>>>(srcp, dstp, ea, V2, aes2, a_s, a_d, slot,
                                          csr_alpha, E_, N_);
    dst_aggregate<<<(N_ + 3) / 4, 256, 0, stream>>>(rowptr, csr_src, csr_alpha, A, Bb, N_);
    pool_kernel<<<64 * POOL_SPLITS, 256, 0, stream>>>(Bb, gstart, pooled);

    // ---- graph MLP ----
    mlp_kernel<<<64, 64, 0, stream>>>(pooled, gstart, b2, W3, b3, W4, b4, (float*)d_out);
}

// Round 4
// 431.628 us; speedup vs baseline: 2.2017x; 1.1150x over previous
//
#include <hip/hip_runtime.h>
#include <hip/hip_bf16.h>

#define NEG_SLOPE 0.2f

// ---------------------------------------------------------------------------
// edge_attr column sums (for mean over E rows)
__global__ __launch_bounds__(256) void ea_colsum(const float* __restrict__ ea,
                                                 float* __restrict__ sums, int E_) {
    int j = threadIdx.x & 15, rl = threadIdx.x >> 4;
    float acc = 0.f;
    for (long long r = (long long)blockIdx.x * 16 + rl; r < E_; r += (long long)gridDim.x * 16)
        acc += ea[r * 16 + j];
    __shared__ float red[256];
    red[rl * 16 + j] = acc;
    __syncthreads();
    if (threadIdx.x < 16) {
        float s = 0.f;
#pragma unroll
        for (int i = 0; i < 16; i++) s += red[i * 16 + threadIdx.x];
        atomicAdd(&sums[threadIdx.x], s);
    }
}

// ---------------------------------------------------------------------------
// V[d,h] = sum_c W_e[d,128]|(h*32+c) * att_e[h*32+c]; aes[h] = mean_ea @ V
__global__ void prep_kernel(const float* __restrict__ We1, const float* __restrict__ ate1,
                            const float* __restrict__ We2, const float* __restrict__ ate2,
                            const float* __restrict__ ea_sums, float invE,
                            float* __restrict__ V1, float* __restrict__ V2,
                            float* __restrict__ aes1, float* __restrict__ aes2) {
    int tid = threadIdx.x;
    __shared__ float V1s[64], V2s[64];
    if (tid < 64) {
        int dd = tid >> 2, h = tid & 3;
        float s = 0.f;
        for (int c = 0; c < 32; c++) s += We1[dd * 128 + h * 32 + c] * ate1[h * 32 + c];
        V1[dd * 4 + h] = s; V1s[dd * 4 + h] = s;
    } else if (tid < 128) {
        int t = tid - 64, dd = t >> 2, h = t & 3;
        float s = 0.f;
        for (int c = 0; c < 32; c++) s += We2[dd * 128 + h * 32 + c] * ate2[h * 32 + c];
        V2[dd * 4 + h] = s; V2s[dd * 4 + h] = s;
    }
    __syncthreads();
    if (tid < 4) {
        float s = 0.f;
        for (int dd = 0; dd < 16; dd++) s += ea_sums[dd] * invE * V1s[dd * 4 + tid];
        aes1[tid] = s;
    } else if (tid >= 64 && tid < 68) {
        int h = tid - 64;
        float s = 0.f;
        for (int dd = 0; dd < 16; dd++) s += ea_sums[dd] * invE * V2s[dd * 4 + h];
        aes2[h] = s;
    }
}

// ---------------------------------------------------------------------------
// CSR build
__global__ void deg_kernel(const int* __restrict__ dst, int* __restrict__ deg, int E_, int n) {
    int e = blockIdx.x * blockDim.x + threadIdx.x;
    if (e >= E_ + n) return;
    int d = (e < E_) ? dst[e] : e - E_;
    atomicAdd(&deg[d], 1);
}

// ---- 3-phase parallel exclusive scan over deg[0..n) -> rowptr, cursor ----
#define SCAN_PER 8
#define SCAN_CHUNK 2048  // 256 threads * 8

__global__ __launch_bounds__(256) void scan_part(const int* __restrict__ deg,
                                                 int* __restrict__ rowptr,
                                                 int* __restrict__ blocksum, int n) {
    int tid = threadIdx.x;
    int base = blockIdx.x * SCAN_CHUNK + tid * SCAN_PER;
    int v[SCAN_PER];
    int s = 0;
#pragma unroll
    for (int k = 0; k < SCAN_PER; k++) {
        int i = base + k;
        int d = (i < n) ? deg[i] : 0;
        v[k] = s;
        s += d;
    }
    __shared__ int part[256];
    part[tid] = s;
    __syncthreads();
    for (int off = 1; off < 256; off <<= 1) {
        int t = (tid >= off) ? part[tid - off] : 0;
        __syncthreads();
        part[tid] += t;
        __syncthreads();
    }
    int prefix = (tid == 0) ? 0 : part[tid - 1];
#pragma unroll
    for (int k = 0; k < SCAN_PER; k++) {
        int i = base + k;
        if (i < n) rowptr[i] = prefix + v[k];
    }
    if (tid == 255) blocksum[blockIdx.x] = part[255];
}

__global__ void scan_mid(int* __restrict__ blocksum, int nb) {
    if (threadIdx.x == 0) {
        int acc = 0;
        for (int b = 0; b < nb; b++) { int t = blocksum[b]; blocksum[b] = acc; acc += t; }
    }
}

__global__ __launch_bounds__(256) void scan_add(int* __restrict__ rowptr,
                                                int* __restrict__ cursor,
                                                const int* __restrict__ blocksum,
                                                int n, int total) {
    int base = blockIdx.x * SCAN_CHUNK + threadIdx.x * SCAN_PER;
    int off = blocksum[blockIdx.x];
#pragma unroll
    for (int k = 0; k < SCAN_PER; k++) {
        int j = base + k;
        if (j < n) { int r = rowptr[j] + off; rowptr[j] = r; cursor[j] = r; }
    }
    if (blockIdx.x == 0 && threadIdx.x == 0) rowptr[n] = total;
}

__global__ void scatter_kernel(const int* __restrict__ src, const int* __restrict__ dst,
                               int* __restrict__ cursor, int* __restrict__ csr_src,
                               int* __restrict__ slot, int E_, int n) {
    int e = blockIdx.x * blockDim.x + threadIdx.x;
    if (e >= E_ + n) return;
    int s, d;
    if (e < E_) { s = src[e]; d = dst[e]; } else { s = d = e - E_; }
    int i = atomicAdd(&cursor[d], 1);
    csr_src[i] = s;
    slot[e] = i;
}

// ---------------------------------------------------------------------------
// graph boundaries in sorted batch: gstart[g] = lower_bound(batch, g)
__global__ void bounds_kernel(const int* __restrict__ batch, int* __restrict__ gstart, int n) {
    int g = threadIdx.x;
    if (g > 64) return;
    if (g == 64) { gstart[64] = n; return; }
    int lo = 0, hi = n;
    while (lo < hi) {
        int mid = (lo + hi) >> 1;
        if (batch[mid] < g) lo = mid + 1; else hi = mid;
    }
    gstart[g] = lo;
}

// ---------------------------------------------------------------------------
// xw = X @ W  (128x128), plus per-head attention dots a_src/a_dst
__global__ __launch_bounds__(256) void gemm_att(const float* __restrict__ X,
                                                const float* __restrict__ W,
                                                const float* __restrict__ att_s,
                                                const float* __restrict__ att_d,
                                                float* __restrict__ XW,
                                                float* __restrict__ a_s,
                                                float* __restrict__ a_d, int n) {
    __shared__ float Wl[128 * 128];
    __shared__ float Xt[128][32];   // [k][row]
    int tid = threadIdx.x;
    {
        const float4* Wv = (const float4*)W;
        float4* Wlv = (float4*)Wl;
#pragma unroll
        for (int i = 0; i < 16; i++) Wlv[tid + i * 256] = Wv[tid + i * 256];
    }
    int cg = tid & 31;   // cols cg*4 .. cg*4+3
    int rg = tid >> 5;   // rows rg*4 .. rg*4+3 (of 32)
    float4 as4 = *(const float4*)(att_s + cg * 4);
    float4 ad4 = *(const float4*)(att_d + cg * 4);

    for (int half = 0; half < 2; half++) {
        int rowbase = blockIdx.x * 64 + half * 32;
        {
            int r = tid & 31, kb = (tid >> 5) * 16;
            int row = rowbase + r;
            __syncthreads();
#pragma unroll
            for (int q = 0; q < 4; q++) {
                float4 v = make_float4(0.f, 0.f, 0.f, 0.f);
                if (row < n) v = *(const float4*)(X + (size_t)row * 128 + kb + q * 4);
                Xt[kb + q * 4 + 0][r] = v.x;
                Xt[kb + q * 4 + 1][r] = v.y;
                Xt[kb + q * 4 + 2][r] = v.z;
                Xt[kb + q * 4 + 3][r] = v.w;
            }
            __syncthreads();
        }
        float acc[4][4];
#pragma unroll
        for (int r = 0; r < 4; r++)
#pragma unroll
            for (int c = 0; c < 4; c++) acc[r][c] = 0.f;

#pragma unroll 8
        for (int k = 0; k < 128; k++) {
            float4 xv = *(const float4*)(&Xt[k][rg * 4]);
            float4 wv = *(const float4*)(&Wl[k * 128 + cg * 4]);
            acc[0][0] += xv.x * wv.x; acc[0][1] += xv.x * wv.y; acc[0][2] += xv.x * wv.z; acc[0][3] += xv.x * wv.w;
            acc[1][0] += xv.y * wv.x; acc[1][1] += xv.y * wv.y; acc[1][2] += xv.y * wv.z; acc[1][3] += xv.y * wv.w;
            acc[2][0] += xv.z * wv.x; acc[2][1] += xv.z * wv.y; acc[2][2] += xv.z * wv.z; acc[2][3] += xv.z * wv.w;
            acc[3][0] += xv.w * wv.x; acc[3][1] += xv.w * wv.y; acc[3][2] += xv.w * wv.z; acc[3][3] += xv.w * wv.w;
        }
#pragma unroll
        for (int r = 0; r < 4; r++) {
            int row = rowbase + rg * 4 + r;
            float ss = acc[r][0] * as4.x + acc[r][1] * as4.y + acc[r][2] * as4.z + acc[r][3] * as4.w;
            float sd = acc[r][0] * ad4.x + acc[r][1] * ad4.y + acc[r][2] * ad4.z + acc[r][3] * ad4.w;
            ss += __shfl_xor(ss, 1, 8); ss += __shfl_xor(ss, 2, 8); ss += __shfl_xor(ss, 4, 8);
            sd += __shfl_xor(sd, 1, 8); sd += __shfl_xor(sd, 2, 8); sd += __shfl_xor(sd, 4, 8);
            if (row < n) {
                *(float4*)(XW + (size_t)row * 128 + cg * 4) =
                    make_float4(acc[r][0], acc[r][1], acc[r][2], acc[r][3]);
                if ((cg & 7) == 0) {
                    a_s[row * 4 + (cg >> 3)] = ss;
                    a_d[row * 4 + (cg >> 3)] = sd;
                }
            }
        }
    }
}

// ---------------------------------------------------------------------------
// per-edge alpha (pre-softmax, leaky-relu'd), written in CSR order
__global__ __launch_bounds__(256) void alpha_kernel(
    const int* __restrict__ src, const int* __restrict__ dst,
    const float* __restrict__ ea, const float* __restrict__ V,
    const float* __restrict__ aes, const float* __restrict__ a_s,
    const float* __restrict__ a_d, const int* __restrict__ slot,
    float* __restrict__ csr_alpha, int E_, int n) {
    __shared__ float Vl[64];
    __shared__ float aesl[4];
    int tid = threadIdx.x;
    if (tid < 64) Vl[tid] = V[tid];
    if (tid < 4) aesl[tid] = aes[tid];
    __syncthreads();
    int e = blockIdx.x * 256 + tid;
    if (e >= E_ + n) return;
    int s, d;
    float ae[4];
    if (e < E_) {
        s = src[e]; d = dst[e];
        ae[0] = ae[1] = ae[2] = ae[3] = 0.f;
        const float4* er = (const float4*)(ea + (size_t)e * 16);
#pragma unroll
        for (int q = 0; q < 4; q++) {
            float4 v = er[q];
#pragma unroll
            for (int h = 0; h < 4; h++) {
                ae[h] += v.x * Vl[(q * 4 + 0) * 4 + h] + v.y * Vl[(q * 4 + 1) * 4 + h] +
                         v.z * Vl[(q * 4 + 2) * 4 + h] + v.w * Vl[(q * 4 + 3) * 4 + h];
            }
        }
    } else {
        s = d = e - E_;
        ae[0] = aesl[0]; ae[1] = aesl[1]; ae[2] = aesl[2]; ae[3] = aesl[3];
    }
    float4 asv = *(const float4*)(a_s + (size_t)s * 4);
    float4 adv = *(const float4*)(a_d + (size_t)d * 4);
    float o0 = asv.x + adv.x + ae[0];
    float o1 = asv.y + adv.y + ae[1];
    float o2 = asv.z + adv.z + ae[2];
    float o3 = asv.w + adv.w + ae[3];
    o0 = o0 > 0.f ? o0 : NEG_SLOPE * o0;
    o1 = o1 > 0.f ? o1 : NEG_SLOPE * o1;
    o2 = o2 > 0.f ? o2 : NEG_SLOPE * o2;
    o3 = o3 > 0.f ? o3 : NEG_SLOPE * o3;
    *(float4*)(csr_alpha + (size_t)slot[e] * 4) = make_float4(o0, o1, o2, o3);
}

// ---------------------------------------------------------------------------
// wave-cooperative segment softmax + gather.
// lane = (h = lane>>4, j = lane&15); 16-edge chunks; w/src broadcast by shuffle.
// mode 1: fused bias+relu epilogue (layer 1); mode 0: plain write (layer 2).
__global__ __launch_bounds__(256) void dst_aggregate(
    const int* __restrict__ rowptr, const int* __restrict__ csr_src,
    const float* __restrict__ csr_alpha, const float* __restrict__ XW,
    const float* __restrict__ bias, float* __restrict__ OUT, int n, int mode) {
    int wv = threadIdx.x >> 6, lane = threadIdx.x & 63;
    int d = blockIdx.x * 4 + wv;
    if (d >= n) return;
    int h = lane >> 4;    // own head (for staging) == head of own channel pair
    int j = lane & 15;    // edge slot within chunk / channel-pair index
    int beg = rowptr[d], end = rowptr[d + 1];

    // Phase A: per-head max (fully coalesced: 16 edges x 4 heads per 256B load)
    float m = -1e30f;
    for (int i = beg + j; i < end; i += 16)
        m = fmaxf(m, csr_alpha[(size_t)i * 4 + h]);
    m = fmaxf(m, __shfl_xor(m, 1));
    m = fmaxf(m, __shfl_xor(m, 2));
    m = fmaxf(m, __shfl_xor(m, 4));
    m = fmaxf(m, __shfl_xor(m, 8));

    float2 acc = make_float2(0.f, 0.f);
    float den = 0.f;
    const float* xwp = XW + h * 32 + j * 2;   // + s*128 per edge
    int gb = lane & 48;                       // group base for w broadcast

    for (int cbeg = beg; cbeg < end; cbeg += 16) {
        int cnt = min(16, end - cbeg);
        float w = 0.f; int srcreg = 0;
        if (j < cnt) {
            w = __expf(csr_alpha[(size_t)(cbeg + j) * 4 + h] - m);
            srcreg = csr_src[cbeg + j];
        }
        den += w;
#pragma unroll 4
        for (int k = 0; k < cnt; k++) {
            int s = __shfl(srcreg, k);            // lane k holds slot k
            float wk = __shfl(w, gb | k);         // own-head w of edge k
            float2 v = *(const float2*)(xwp + (size_t)s * 128);
            acc.x += wk * v.x;
            acc.y += wk * v.y;
        }
    }
    den += __shfl_xor(den, 1);
    den += __shfl_xor(den, 2);
    den += __shfl_xor(den, 4);
    den += __shfl_xor(den, 8);
    float inv = 1.f / (den + 1e-16f);
    int c = h * 32 + j * 2;
    float o0 = acc.x * inv, o1 = acc.y * inv;
    if (mode == 1) {
        o0 = fmaxf(o0 + bias[c], 0.f);
        o1 = fmaxf(o1 + bias[c + 1], 0.f);
    }
    *(float2*)(OUT + (size_t)d * 128 + c) = make_float2(o0, o1);
}

// ---------------------------------------------------------------------------
// pooled[g,c] = sum over nodes of graph g of head-mean; one block per (g,split)
#define POOL_SPLITS 8
__global__ __launch_bounds__(256) void pool_kernel(const float* __restrict__ B,
                                                   const int* __restrict__ gstart,
                                                   float* __restrict__ pooled) {
    int g = blockIdx.x / POOL_SPLITS, sp = blockIdx.x % POOL_SPLITS;
    int lo = gstart[g], hi = gstart[g + 1];
    int cnt = hi - lo;
    int per = (cnt + POOL_SPLITS - 1) / POOL_SPLITS;
    int s0 = lo + sp * per;
    int s1 = min(s0 + per, hi);
    int c = threadIdx.x & 31, rl = threadIdx.x >> 5;
    float acc = 0.f;
    for (int node = s0 + rl; node < s1; node += 8) {
        const float* r = B + (size_t)node * 128;
        acc += 0.25f * (r[c] + r[c + 32] + r[c + 64] + r[c + 96]);
    }
    __shared__ float red[8][32];
    red[rl][c] = acc;
    __syncthreads();
    if (threadIdx.x < 32) {
        float s = 0.f;
#pragma unroll
        for (int i = 0; i < 8; i++) s += red[i][threadIdx.x];
        atomicAdd(&pooled[g * 32 + threadIdx.x], s);
    }
}

__global__ void mlp_kernel(const float* __restrict__ pooled, const int* __restrict__ gstart,
                           const float* __restrict__ b2,
                           const float* __restrict__ W3, const float* __restrict__ b3,
                           const float* __restrict__ W4, const float* __restrict__ b4,
                           float* __restrict__ out) {
    int g = blockIdx.x;
    int c = threadIdx.x;
    __shared__ float pm[32];
    __shared__ float t[32];
    int cnt = gstart[g + 1] - gstart[g];
    if (c < 32) {
        float m = 0.f;
        if (cnt > 0) m = pooled[g * 32 + c] / (float)cnt + b2[c];
        pm[c] = m;
    }
    __syncthreads();
    if (c < 32) {
        float s = b3[c];
        for (int k = 0; k < 32; k++) s += pm[k] * W3[k * 32 + c];
        t[c] = fmaxf(s, 0.f);
    }
    __syncthreads();
    if (c < 2) {
        float o = b4[c];
        for (int k = 0; k < 32; k++) o += t[k] * W4[k * 2 + c];
        out[g * 2 + c] = o;
    }
}

// ---------------------------------------------------------------------------
extern "C" void kernel_launch(void* const* d_in, const int* in_sizes, int n_in,
                              void* d_out, int out_size, void* d_ws, size_t ws_size,
                              hipStream_t stream) {
    const float* x    = (const float*)d_in[0];
    const int*   eidx = (const int*)d_in[1];
    const float* ea   = (const float*)d_in[2];
    const int*   batch= (const int*)d_in[3];
    const float* W1   = (const float*)d_in[4];
    const float* as1  = (const float*)d_in[5];
    const float* ad1  = (const float*)d_in[6];
    const float* We1  = (const float*)d_in[7];
    const float* ate1 = (const float*)d_in[8];
    const float* b1   = (const float*)d_in[9];
    const float* W2   = (const float*)d_in[10];
    const float* as2  = (const float*)d_in[11];
    const float* ad2  = (const float*)d_in[12];
    const float* We2  = (const float*)d_in[13];
    const float* ate2 = (const float*)d_in[14];
    const float* b2   = (const float*)d_in[15];
    const float* W3   = (const float*)d_in[16];
    const float* b3   = (const float*)d_in[17];
    const float* W4   = (const float*)d_in[18];
    const float* b4   = (const float*)d_in[19];

    const int N_ = in_sizes[0] / 128;
    const int E_ = in_sizes[1] / 2;
    const int EN = E_ + N_;
    const int* srcp = eidx;
    const int* dstp = eidx + E_;

    char* w = (char*)d_ws;
    size_t off = 0;
    auto alloc = [&](size_t bytes) -> void* {
        void* p = w + off;
        off = (off + bytes + 255) & ~(size_t)255;
        return p;
    };
    float* A         = (float*)alloc((size_t)N_ * 128 * 4);
    float* Bb        = (float*)alloc((size_t)N_ * 128 * 4);
    float* csr_alpha = (float*)alloc((size_t)EN * 16);
    int*   csr_src   = (int*)alloc((size_t)EN * 4);
    int*   slot      = (int*)alloc((size_t)EN * 4);
    int*   rowptr    = (int*)alloc((size_t)(N_ + 1) * 4);
    int*   cursor    = (int*)alloc((size_t)N_ * 4);
    int*   deg       = (int*)alloc((size_t)N_ * 4);
    int*   blocksum  = (int*)alloc(((size_t)N_ / SCAN_CHUNK + 2) * 4);
    float* a_s       = (float*)alloc((size_t)N_ * 16);
    float* a_d       = (float*)alloc((size_t)N_ * 16);
    float* ea_sums   = (float*)alloc(64);
    float* V1        = (float*)alloc(256);
    float* V2        = (float*)alloc(256);
    float* aes1      = (float*)alloc(16);
    float* aes2      = (float*)alloc(16);
    float* pooled    = (float*)alloc(64 * 32 * 4);
    int*   gstart    = (int*)alloc(65 * 4);

    hipMemsetAsync(deg, 0, (size_t)N_ * 4, stream);
    hipMemsetAsync(ea_sums, 0, 64, stream);
    hipMemsetAsync(pooled, 0, 64 * 32 * 4, stream);

    int ebk = (EN + 255) / 256;
    int nsb = (N_ + SCAN_CHUNK - 1) / SCAN_CHUNK;

    ea_colsum<<<1024, 256, 0, stream>>>(ea, ea_sums, E_);
    deg_kernel<<<ebk, 256, 0, stream>>>(dstp, deg, E_, N_);
    scan_part<<<nsb, 256, 0, stream>>>(deg, rowptr, blocksum, N_);
    scan_mid<<<1, 64, 0, stream>>>(blocksum, nsb);
    scan_add<<<nsb, 256, 0, stream>>>(rowptr, cursor, blocksum, N_, EN);
    scatter_kernel<<<ebk, 256, 0, stream>>>(srcp, dstp, cursor, csr_src, slot, E_, N_);
    prep_kernel<<<1, 128, 0, stream>>>(We1, ate1, We2, ate2, ea_sums, 1.0f / (float)E_,
                                       V1, V2, aes1, aes2);
    bounds_kernel<<<1, 128, 0, stream>>>(batch, gstart, N_);

    // ---- layer 1 ----
    gemm_att<<<(N_ + 63) / 64, 256, 0, stream>>>(x, W1, as1, ad1, A, a_s, a_d, N_);
    alpha_kernel<<<ebk, 256, 0, stream>>>(srcp, dstp, ea, V1, aes1, a_s, a_d, slot,
                                          csr_alpha, E_, N_);
    dst_aggregate<<<(N_ + 3) / 4, 256, 0, stream>>>(rowptr, csr_src, csr_alpha, A, b1, Bb,
                                                    N_, 1);

    // ---- layer 2 ----
    gemm_att<<<(N_ + 63) / 64, 256, 0, stream>>>(Bb, W2, as2, ad2, A, a_s, a_d, N_);
    alpha_kernel<<<ebk, 256, 0, stream>>>(srcp, dstp, ea, V2, aes2, a_s, a_d, slot,
                                          csr_alpha, E_, N_);
    dst_aggregate<<<(N_ + 3) / 4, 256, 0, stream>>>(rowptr, csr_src, csr_alpha, A, b2, Bb,
                                                    N_, 0);
    pool_kernel<<<64 * POOL_SPLITS, 256, 0, stream>>>(Bb, gstart, pooled);

    // ---- graph MLP ----
    mlp_kernel<<<64, 64, 0, stream>>>(pooled, gstart, b2, W3, b3, W4, b4, (float*)d_out);
}

// Round 5
// 376.326 us; speedup vs baseline: 2.5253x; 1.1470x over previous
//
#include <hip/hip_runtime.h>
#include <hip/hip_bf16.h>

#define NEG_SLOPE 0.2f

__device__ __forceinline__ unsigned short bf16rne(float x) {
    unsigned int u = __float_as_uint(x);
    u += 0x7fffu + ((u >> 16) & 1u);
    return (unsigned short)(u >> 16);
}

// ---------------------------------------------------------------------------
// edge_attr column sums (for mean over E rows)
__global__ __launch_bounds__(256) void ea_colsum(const float* __restrict__ ea,
                                                 float* __restrict__ sums, int E_) {
    int j = threadIdx.x & 15, rl = threadIdx.x >> 4;
    float acc = 0.f;
    for (long long r = (long long)blockIdx.x * 16 + rl; r < E_; r += (long long)gridDim.x * 16)
        acc += ea[r * 16 + j];
    __shared__ float red[256];
    red[rl * 16 + j] = acc;
    __syncthreads();
    if (threadIdx.x < 16) {
        float s = 0.f;
#pragma unroll
        for (int i = 0; i < 16; i++) s += red[i * 16 + threadIdx.x];
        atomicAdd(&sums[threadIdx.x], s);
    }
}

// ---------------------------------------------------------------------------
// V[d,h] = sum_c W_e[d,128]|(h*32+c) * att_e[h*32+c]; aes[h] = mean_ea @ V
__global__ void prep_kernel(const float* __restrict__ We1, const float* __restrict__ ate1,
                            const float* __restrict__ We2, const float* __restrict__ ate2,
                            const float* __restrict__ ea_sums, float invE,
                            float* __restrict__ V1, float* __restrict__ V2,
                            float* __restrict__ aes1, float* __restrict__ aes2) {
    int tid = threadIdx.x;
    __shared__ float V1s[64], V2s[64];
    if (tid < 64) {
        int dd = tid >> 2, h = tid & 3;
        float s = 0.f;
        for (int c = 0; c < 32; c++) s += We1[dd * 128 + h * 32 + c] * ate1[h * 32 + c];
        V1[dd * 4 + h] = s; V1s[dd * 4 + h] = s;
    } else if (tid < 128) {
        int t = tid - 64, dd = t >> 2, h = t & 3;
        float s = 0.f;
        for (int c = 0; c < 32; c++) s += We2[dd * 128 + h * 32 + c] * ate2[h * 32 + c];
        V2[dd * 4 + h] = s; V2s[dd * 4 + h] = s;
    }
    __syncthreads();
    if (tid < 4) {
        float s = 0.f;
        for (int dd = 0; dd < 16; dd++) s += ea_sums[dd] * invE * V1s[dd * 4 + tid];
        aes1[tid] = s;
    } else if (tid >= 64 && tid < 68) {
        int h = tid - 64;
        float s = 0.f;
        for (int dd = 0; dd < 16; dd++) s += ea_sums[dd] * invE * V2s[dd * 4 + h];
        aes2[h] = s;
    }
}

// ---------------------------------------------------------------------------
// CSR build
__global__ void deg_kernel(const int* __restrict__ dst, int* __restrict__ deg, int E_, int n) {
    int e = blockIdx.x * blockDim.x + threadIdx.x;
    if (e >= E_ + n) return;
    int d = (e < E_) ? dst[e] : e - E_;
    atomicAdd(&deg[d], 1);
}

// ---- 3-phase parallel exclusive scan over deg[0..n) -> rowptr, cursor ----
#define SCAN_PER 8
#define SCAN_CHUNK 2048  // 256 threads * 8

__global__ __launch_bounds__(256) void scan_part(const int* __restrict__ deg,
                                                 int* __restrict__ rowptr,
                                                 int* __restrict__ blocksum, int n) {
    int tid = threadIdx.x;
    int base = blockIdx.x * SCAN_CHUNK + tid * SCAN_PER;
    int v[SCAN_PER];
    int s = 0;
#pragma unroll
    for (int k = 0; k < SCAN_PER; k++) {
        int i = base + k;
        int d = (i < n) ? deg[i] : 0;
        v[k] = s;
        s += d;
    }
    __shared__ int part[256];
    part[tid] = s;
    __syncthreads();
    for (int off = 1; off < 256; off <<= 1) {
        int t = (tid >= off) ? part[tid - off] : 0;
        __syncthreads();
        part[tid] += t;
        __syncthreads();
    }
    int prefix = (tid == 0) ? 0 : part[tid - 1];
#pragma unroll
    for (int k = 0; k < SCAN_PER; k++) {
        int i = base + k;
        if (i < n) rowptr[i] = prefix + v[k];
    }
    if (tid == 255) blocksum[blockIdx.x] = part[255];
}

__global__ void scan_mid(int* __restrict__ blocksum, int nb) {
    if (threadIdx.x == 0) {
        int acc = 0;
        for (int b = 0; b < nb; b++) { int t = blocksum[b]; blocksum[b] = acc; acc += t; }
    }
}

__global__ __launch_bounds__(256) void scan_add(int* __restrict__ rowptr,
                                                int* __restrict__ cursor,
                                                const int* __restrict__ blocksum,
                                                int n, int total) {
    int base = blockIdx.x * SCAN_CHUNK + threadIdx.x * SCAN_PER;
    int off = blocksum[blockIdx.x];
#pragma unroll
    for (int k = 0; k < SCAN_PER; k++) {
        int j = base + k;
        if (j < n) { int r = rowptr[j] + off; rowptr[j] = r; cursor[j] = r; }
    }
    if (blockIdx.x == 0 && threadIdx.x == 0) rowptr[n] = total;
}

__global__ void scatter_kernel(const int* __restrict__ src, const int* __restrict__ dst,
                               int* __restrict__ cursor, int* __restrict__ csr_src,
                               int* __restrict__ slot, int E_, int n) {
    int e = blockIdx.x * blockDim.x + threadIdx.x;
    if (e >= E_ + n) return;
    int s, d;
    if (e < E_) { s = src[e]; d = dst[e]; } else { s = d = e - E_; }
    int i = atomicAdd(&cursor[d], 1);
    csr_src[i] = s;
    slot[e] = i;
}

// ---------------------------------------------------------------------------
// graph boundaries in sorted batch: gstart[g] = lower_bound(batch, g)
__global__ void bounds_kernel(const int* __restrict__ batch, int* __restrict__ gstart, int n) {
    int g = threadIdx.x;
    if (g > 64) return;
    if (g == 64) { gstart[64] = n; return; }
    int lo = 0, hi = n;
    while (lo < hi) {
        int mid = (lo + hi) >> 1;
        if (batch[mid] < g) lo = mid + 1; else hi = mid;
    }
    gstart[g] = lo;
}

// ---------------------------------------------------------------------------
// xw = X @ W  (128x128) -> bf16-packed XW, plus per-head dots a_src/a_dst (f32)
__global__ __launch_bounds__(256) void gemm_att(const float* __restrict__ X,
                                                const float* __restrict__ W,
                                                const float* __restrict__ att_s,
                                                const float* __restrict__ att_d,
                                                unsigned short* __restrict__ XWb,
                                                float* __restrict__ a_s,
                                                float* __restrict__ a_d, int n) {
    __shared__ float Wl[128 * 128];
    __shared__ float Xt[128][32];   // [k][row]
    int tid = threadIdx.x;
    {
        const float4* Wv = (const float4*)W;
        float4* Wlv = (float4*)Wl;
#pragma unroll
        for (int i = 0; i < 16; i++) Wlv[tid + i * 256] = Wv[tid + i * 256];
    }
    int cg = tid & 31;   // cols cg*4 .. cg*4+3
    int rg = tid >> 5;   // rows rg*4 .. rg*4+3 (of 32)
    float4 as4 = *(const float4*)(att_s + cg * 4);
    float4 ad4 = *(const float4*)(att_d + cg * 4);

    for (int half = 0; half < 2; half++) {
        int rowbase = blockIdx.x * 64 + half * 32;
        {
            int r = tid & 31, kb = (tid >> 5) * 16;
            int row = rowbase + r;
            __syncthreads();
#pragma unroll
            for (int q = 0; q < 4; q++) {
                float4 v = make_float4(0.f, 0.f, 0.f, 0.f);
                if (row < n) v = *(const float4*)(X + (size_t)row * 128 + kb + q * 4);
                Xt[kb + q * 4 + 0][r] = v.x;
                Xt[kb + q * 4 + 1][r] = v.y;
                Xt[kb + q * 4 + 2][r] = v.z;
                Xt[kb + q * 4 + 3][r] = v.w;
            }
            __syncthreads();
        }
        float acc[4][4];
#pragma unroll
        for (int r = 0; r < 4; r++)
#pragma unroll
            for (int c = 0; c < 4; c++) acc[r][c] = 0.f;

#pragma unroll 8
        for (int k = 0; k < 128; k++) {
            float4 xv = *(const float4*)(&Xt[k][rg * 4]);
            float4 wv = *(const float4*)(&Wl[k * 128 + cg * 4]);
            acc[0][0] += xv.x * wv.x; acc[0][1] += xv.x * wv.y; acc[0][2] += xv.x * wv.z; acc[0][3] += xv.x * wv.w;
            acc[1][0] += xv.y * wv.x; acc[1][1] += xv.y * wv.y; acc[1][2] += xv.y * wv.z; acc[1][3] += xv.y * wv.w;
            acc[2][0] += xv.z * wv.x; acc[2][1] += xv.z * wv.y; acc[2][2] += xv.z * wv.z; acc[2][3] += xv.z * wv.w;
            acc[3][0] += xv.w * wv.x; acc[3][1] += xv.w * wv.y; acc[3][2] += xv.w * wv.z; acc[3][3] += xv.w * wv.w;
        }
#pragma unroll
        for (int r = 0; r < 4; r++) {
            int row = rowbase + rg * 4 + r;
            float ss = acc[r][0] * as4.x + acc[r][1] * as4.y + acc[r][2] * as4.z + acc[r][3] * as4.w;
            float sd = acc[r][0] * ad4.x + acc[r][1] * ad4.y + acc[r][2] * ad4.z + acc[r][3] * ad4.w;
            ss += __shfl_xor(ss, 1, 8); ss += __shfl_xor(ss, 2, 8); ss += __shfl_xor(ss, 4, 8);
            sd += __shfl_xor(sd, 1, 8); sd += __shfl_xor(sd, 2, 8); sd += __shfl_xor(sd, 4, 8);
            if (row < n) {
                ushort4 pk;
                pk.x = bf16rne(acc[r][0]);
                pk.y = bf16rne(acc[r][1]);
                pk.z = bf16rne(acc[r][2]);
                pk.w = bf16rne(acc[r][3]);
                *(ushort4*)(XWb + (size_t)row * 128 + cg * 4) = pk;
                if ((cg & 7) == 0) {
                    a_s[row * 4 + (cg >> 3)] = ss;
                    a_d[row * 4 + (cg >> 3)] = sd;
                }
            }
        }
    }
}

// ---------------------------------------------------------------------------
// per-edge alpha (pre-softmax, leaky-relu'd), written in CSR order
__global__ __launch_bounds__(256) void alpha_kernel(
    const int* __restrict__ src, const int* __restrict__ dst,
    const float* __restrict__ ea, const float* __restrict__ V,
    const float* __restrict__ aes, const float* __restrict__ a_s,
    const float* __restrict__ a_d, const int* __restrict__ slot,
    float* __restrict__ csr_alpha, int E_, int n) {
    __shared__ float Vl[64];
    __shared__ float aesl[4];
    int tid = threadIdx.x;
    if (tid < 64) Vl[tid] = V[tid];
    if (tid < 4) aesl[tid] = aes[tid];
    __syncthreads();
    int e = blockIdx.x * 256 + tid;
    if (e >= E_ + n) return;
    int s, d;
    float ae[4];
    if (e < E_) {
        s = src[e]; d = dst[e];
        ae[0] = ae[1] = ae[2] = ae[3] = 0.f;
        const float4* er = (const float4*)(ea + (size_t)e * 16);
#pragma unroll
        for (int q = 0; q < 4; q++) {
            float4 v = er[q];
#pragma unroll
            for (int h = 0; h < 4; h++) {
                ae[h] += v.x * Vl[(q * 4 + 0) * 4 + h] + v.y * Vl[(q * 4 + 1) * 4 + h] +
                         v.z * Vl[(q * 4 + 2) * 4 + h] + v.w * Vl[(q * 4 + 3) * 4 + h];
            }
        }
    } else {
        s = d = e - E_;
        ae[0] = aesl[0]; ae[1] = aesl[1]; ae[2] = aesl[2]; ae[3] = aesl[3];
    }
    float4 asv = *(const float4*)(a_s + (size_t)s * 4);
    float4 adv = *(const float4*)(a_d + (size_t)d * 4);
    float o0 = asv.x + adv.x + ae[0];
    float o1 = asv.y + adv.y + ae[1];
    float o2 = asv.z + adv.z + ae[2];
    float o3 = asv.w + adv.w + ae[3];
    o0 = o0 > 0.f ? o0 : NEG_SLOPE * o0;
    o1 = o1 > 0.f ? o1 : NEG_SLOPE * o1;
    o2 = o2 > 0.f ? o2 : NEG_SLOPE * o2;
    o3 = o3 > 0.f ? o3 : NEG_SLOPE * o3;
    *(float4*)(csr_alpha + (size_t)slot[e] * 4) = make_float4(o0, o1, o2, o3);
}

// ---------------------------------------------------------------------------
// wave-cooperative segment softmax + bf16 gather; alphas are O(1) so exp
// without max-shift is overflow-safe and softmax-identical.
// lane = (h = lane>>4, j = lane&15); 16-edge chunks; w/src broadcast by shuffle.
// mode 1: fused bias+relu epilogue (layer 1); mode 0: plain write (layer 2).
__global__ __launch_bounds__(256) void dst_aggregate(
    const int* __restrict__ rowptr, const int* __restrict__ csr_src,
    const float* __restrict__ csr_alpha, const unsigned int* __restrict__ XW,
    const float* __restrict__ bias, float* __restrict__ OUT, int n, int mode) {
    int wv = threadIdx.x >> 6, lane = threadIdx.x & 63;
    int d = blockIdx.x * 4 + wv;
    if (d >= n) return;
    int h = lane >> 4;    // own head
    int j = lane & 15;    // edge slot within chunk / channel-pair index
    int beg = rowptr[d], end = rowptr[d + 1];
    int gb = lane & 48;   // group base for w broadcast
    const unsigned int dwoff = h * 16 + j;   // dword index within 64-dword row

    float2 acc = make_float2(0.f, 0.f);
    float den = 0.f;

    int i = beg;
    for (; i + 16 <= end; i += 16) {
        float w = __expf(csr_alpha[(size_t)(i + j) * 4 + h]);
        int sreg = csr_src[i + j];
        den += w;
#pragma unroll
        for (int k = 0; k < 16; k++) {
            int s = __shfl(sreg, k);
            float wk = __shfl(w, gb | k);
            unsigned int v = XW[(size_t)s * 64 + dwoff];
            acc.x += wk * __uint_as_float(v << 16);
            acc.y += wk * __uint_as_float(v & 0xffff0000u);
        }
    }
    int cnt = end - i;
    if (cnt > 0) {
        float w = 0.f; int sreg = 0;
        if (j < cnt) {
            w = __expf(csr_alpha[(size_t)(i + j) * 4 + h]);
            sreg = csr_src[i + j];
        }
        den += w;
        for (int k = 0; k < cnt; k++) {
            int s = __shfl(sreg, k);
            float wk = __shfl(w, gb | k);
            unsigned int v = XW[(size_t)s * 64 + dwoff];
            acc.x += wk * __uint_as_float(v << 16);
            acc.y += wk * __uint_as_float(v & 0xffff0000u);
        }
    }
    den += __shfl_xor(den, 1);
    den += __shfl_xor(den, 2);
    den += __shfl_xor(den, 4);
    den += __shfl_xor(den, 8);
    float inv = 1.f / (den + 1e-16f);
    int c = h * 32 + j * 2;
    float o0 = acc.x * inv, o1 = acc.y * inv;
    if (mode == 1) {
        o0 = fmaxf(o0 + bias[c], 0.f);
        o1 = fmaxf(o1 + bias[c + 1], 0.f);
    }
    *(float2*)(OUT + (size_t)d * 128 + c) = make_float2(o0, o1);
}

// ---------------------------------------------------------------------------
// pooled[g,c] = sum over nodes of graph g of head-mean; one block per (g,split)
#define POOL_SPLITS 8
__global__ __launch_bounds__(256) void pool_kernel(const float* __restrict__ B,
                                                   const int* __restrict__ gstart,
                                                   float* __restrict__ pooled) {
    int g = blockIdx.x / POOL_SPLITS, sp = blockIdx.x % POOL_SPLITS;
    int lo = gstart[g], hi = gstart[g + 1];
    int cnt = hi - lo;
    int per = (cnt + POOL_SPLITS - 1) / POOL_SPLITS;
    int s0 = lo + sp * per;
    int s1 = min(s0 + per, hi);
    int c = threadIdx.x & 31, rl = threadIdx.x >> 5;
    float acc = 0.f;
    for (int node = s0 + rl; node < s1; node += 8) {
        const float* r = B + (size_t)node * 128;
        acc += 0.25f * (r[c] + r[c + 32] + r[c + 64] + r[c + 96]);
    }
    __shared__ float red[8][32];
    red[rl][c] = acc;
    __syncthreads();
    if (threadIdx.x < 32) {
        float s = 0.f;
#pragma unroll
        for (int i = 0; i < 8; i++) s += red[i][threadIdx.x];
        atomicAdd(&pooled[g * 32 + threadIdx.x], s);
    }
}

__global__ void mlp_kernel(const float* __restrict__ pooled, const int* __restrict__ gstart,
                           const float* __restrict__ b2,
                           const float* __restrict__ W3, const float* __restrict__ b3,
                           const float* __restrict__ W4, const float* __restrict__ b4,
                           float* __restrict__ out) {
    int g = blockIdx.x;
    int c = threadIdx.x;
    __shared__ float pm[32];
    __shared__ float t[32];
    int cnt = gstart[g + 1] - gstart[g];
    if (c < 32) {
        float m = 0.f;
        if (cnt > 0) m = pooled[g * 32 + c] / (float)cnt + b2[c];
        pm[c] = m;
    }
    __syncthreads();
    if (c < 32) {
        float s = b3[c];
        for (int k = 0; k < 32; k++) s += pm[k] * W3[k * 32 + c];
        t[c] = fmaxf(s, 0.f);
    }
    __syncthreads();
    if (c < 2) {
        float o = b4[c];
        for (int k = 0; k < 32; k++) o += t[k] * W4[k * 2 + c];
        out[g * 2 + c] = o;
    }
}

// ---------------------------------------------------------------------------
extern "C" void kernel_launch(void* const* d_in, const int* in_sizes, int n_in,
                              void* d_out, int out_size, void* d_ws, size_t ws_size,
                              hipStream_t stream) {
    const float* x    = (const float*)d_in[0];
    const int*   eidx = (const int*)d_in[1];
    const float* ea   = (const float*)d_in[2];
    const int*   batch= (const int*)d_in[3];
    const float* W1   = (const float*)d_in[4];
    const float* as1  = (const float*)d_in[5];
    const float* ad1  = (const float*)d_in[6];
    const float* We1  = (const float*)d_in[7];
    const float* ate1 = (const float*)d_in[8];
    const float* b1   = (const float*)d_in[9];
    const float* W2   = (const float*)d_in[10];
    const float* as2  = (const float*)d_in[11];
    const float* ad2  = (const float*)d_in[12];
    const float* We2  = (const float*)d_in[13];
    const float* ate2 = (const float*)d_in[14];
    const float* b2   = (const float*)d_in[15];
    const float* W3   = (const float*)d_in[16];
    const float* b3   = (const float*)d_in[17];
    const float* W4   = (const float*)d_in[18];
    const float* b4   = (const float*)d_in[19];

    const int N_ = in_sizes[0] / 128;
    const int E_ = in_sizes[1] / 2;
    const int EN = E_ + N_;
    const int* srcp = eidx;
    const int* dstp = eidx + E_;

    char* w = (char*)d_ws;
    size_t off = 0;
    auto alloc = [&](size_t bytes) -> void* {
        void* p = w + off;
        off = (off + bytes + 255) & ~(size_t)255;
        return p;
    };
    unsigned short* A = (unsigned short*)alloc((size_t)N_ * 128 * 2);  // bf16 XW
    float* Bb        = (float*)alloc((size_t)N_ * 128 * 4);
    float* csr_alpha = (float*)alloc((size_t)EN * 16);
    int*   csr_src   = (int*)alloc((size_t)EN * 4);
    int*   slot      = (int*)alloc((size_t)EN * 4);
    int*   rowptr    = (int*)alloc((size_t)(N_ + 1) * 4);
    int*   cursor    = (int*)alloc((size_t)N_ * 4);
    int*   deg       = (int*)alloc((size_t)N_ * 4);
    int*   blocksum  = (int*)alloc(((size_t)N_ / SCAN_CHUNK + 2) * 4);
    float* a_s       = (float*)alloc((size_t)N_ * 16);
    float* a_d       = (float*)alloc((size_t)N_ * 16);
    float* ea_sums   = (float*)alloc(64);
    float* V1        = (float*)alloc(256);
    float* V2        = (float*)alloc(256);
    float* aes1      = (float*)alloc(16);
    float* aes2      = (float*)alloc(16);
    float* pooled    = (float*)alloc(64 * 32 * 4);
    int*   gstart    = (int*)alloc(65 * 4);

    hipMemsetAsync(deg, 0, (size_t)N_ * 4, stream);
    hipMemsetAsync(ea_sums, 0, 64, stream);
    hipMemsetAsync(pooled, 0, 64 * 32 * 4, stream);

    int ebk = (EN + 255) / 256;
    int nsb = (N_ + SCAN_CHUNK - 1) / SCAN_CHUNK;

    ea_colsum<<<1024, 256, 0, stream>>>(ea, ea_sums, E_);
    deg_kernel<<<ebk, 256, 0, stream>>>(dstp, deg, E_, N_);
    scan_part<<<nsb, 256, 0, stream>>>(deg, rowptr, blocksum, N_);
    scan_mid<<<1, 64, 0, stream>>>(blocksum, nsb);
    scan_add<<<nsb, 256, 0, stream>>>(rowptr, cursor, blocksum, N_, EN);
    scatter_kernel<<<ebk, 256, 0, stream>>>(srcp, dstp, cursor, csr_src, slot, E_, N_);
    prep_kernel<<<1, 128, 0, stream>>>(We1, ate1, We2, ate2, ea_sums, 1.0f / (float)E_,
                                       V1, V2, aes1, aes2);
    bounds_kernel<<<1, 128, 0, stream>>>(batch, gstart, N_);

    // ---- layer 1 ----
    gemm_att<<<(N_ + 63) / 64, 256, 0, stream>>>(x, W1, as1, ad1, A, a_s, a_d, N_);
    alpha_kernel<<<ebk, 256, 0, stream>>>(srcp, dstp, ea, V1, aes1, a_s, a_d, slot,
                                          csr_alpha, E_, N_);
    dst_aggregate<<<(N_ + 3) / 4, 256, 0, stream>>>(rowptr, csr_src, csr_alpha,
                                                    (const unsigned int*)A, b1, Bb, N_, 1);

    // ---- layer 2 ----
    gemm_att<<<(N_ + 63) / 64, 256, 0, stream>>>(Bb, W2, as2, ad2, A, a_s, a_d, N_);
    alpha_kernel<<<ebk, 256, 0, stream>>>(srcp, dstp, ea, V2, aes2, a_s, a_d, slot,
                                          csr_alpha, E_, N_);
    dst_aggregate<<<(N_ + 3) / 4, 256, 0, stream>>>(rowptr, csr_src, csr_alpha,
                                                    (const unsigned int*)A, b2, Bb, N_, 0);
    pool_kernel<<<64 * POOL_SPLITS, 256, 0, stream>>>(Bb, gstart, pooled);

    // ---- graph MLP ----
    mlp_kernel<<<64, 64, 0, stream>>>(pooled, gstart, b2, W3, b3, W4, b4, (float*)d_out);
}

// Round 6
// 373.041 us; speedup vs baseline: 2.5475x; 1.0088x over previous
//
#include <hip/hip_runtime.h>
#include <hip/hip_bf16.h>

#define NEG_SLOPE 0.2f

__device__ __forceinline__ unsigned short bf16rne(float x) {
    unsigned int u = __float_as_uint(x);
    u += 0x7fffu + ((u >> 16) & 1u);
    return (unsigned short)(u >> 16);
}

// ---------------------------------------------------------------------------
// edge_attr column sums (for mean over E rows)
__global__ __launch_bounds__(256) void ea_colsum(const float* __restrict__ ea,
                                                 float* __restrict__ sums, int E_) {
    int j = threadIdx.x & 15, rl = threadIdx.x >> 4;
    float acc = 0.f;
    for (long long r = (long long)blockIdx.x * 16 + rl; r < E_; r += (long long)gridDim.x * 16)
        acc += ea[r * 16 + j];
    __shared__ float red[256];
    red[rl * 16 + j] = acc;
    __syncthreads();
    if (threadIdx.x < 16) {
        float s = 0.f;
#pragma unroll
        for (int i = 0; i < 16; i++) s += red[i * 16 + threadIdx.x];
        atomicAdd(&sums[threadIdx.x], s);
    }
}

// ---------------------------------------------------------------------------
// V[d,h] = sum_c W_e[d,128]|(h*32+c) * att_e[h*32+c]; aes[h] = mean_ea @ V
__global__ void prep_kernel(const float* __restrict__ We1, const float* __restrict__ ate1,
                            const float* __restrict__ We2, const float* __restrict__ ate2,
                            const float* __restrict__ ea_sums, float invE,
                            float* __restrict__ V1, float* __restrict__ V2,
                            float* __restrict__ aes1, float* __restrict__ aes2) {
    int tid = threadIdx.x;
    __shared__ float V1s[64], V2s[64];
    if (tid < 64) {
        int dd = tid >> 2, h = tid & 3;
        float s = 0.f;
        for (int c = 0; c < 32; c++) s += We1[dd * 128 + h * 32 + c] * ate1[h * 32 + c];
        V1[dd * 4 + h] = s; V1s[dd * 4 + h] = s;
    } else if (tid < 128) {
        int t = tid - 64, dd = t >> 2, h = t & 3;
        float s = 0.f;
        for (int c = 0; c < 32; c++) s += We2[dd * 128 + h * 32 + c] * ate2[h * 32 + c];
        V2[dd * 4 + h] = s; V2s[dd * 4 + h] = s;
    }
    __syncthreads();
    if (tid < 4) {
        float s = 0.f;
        for (int dd = 0; dd < 16; dd++) s += ea_sums[dd] * invE * V1s[dd * 4 + tid];
        aes1[tid] = s;
    } else if (tid >= 64 && tid < 68) {
        int h = tid - 64;
        float s = 0.f;
        for (int dd = 0; dd < 16; dd++) s += ea_sums[dd] * invE * V2s[dd * 4 + h];
        aes2[h] = s;
    }
}

// ---------------------------------------------------------------------------
// CSR build
__global__ void deg_kernel(const int* __restrict__ dst, int* __restrict__ deg, int E_, int n) {
    int e = blockIdx.x * blockDim.x + threadIdx.x;
    if (e >= E_ + n) return;
    int d = (e < E_) ? dst[e] : e - E_;
    atomicAdd(&deg[d], 1);
}

// ---- 3-phase parallel exclusive scan over deg[0..n) -> rowptr, cursor ----
#define SCAN_PER 8
#define SCAN_CHUNK 2048  // 256 threads * 8

__global__ __launch_bounds__(256) void scan_part(const int* __restrict__ deg,
                                                 int* __restrict__ rowptr,
                                                 int* __restrict__ blocksum, int n) {
    int tid = threadIdx.x;
    int base = blockIdx.x * SCAN_CHUNK + tid * SCAN_PER;
    int v[SCAN_PER];
    int s = 0;
#pragma unroll
    for (int k = 0; k < SCAN_PER; k++) {
        int i = base + k;
        int d = (i < n) ? deg[i] : 0;
        v[k] = s;
        s += d;
    }
    __shared__ int part[256];
    part[tid] = s;
    __syncthreads();
    for (int off = 1; off < 256; off <<= 1) {
        int t = (tid >= off) ? part[tid - off] : 0;
        __syncthreads();
        part[tid] += t;
        __syncthreads();
    }
    int prefix = (tid == 0) ? 0 : part[tid - 1];
#pragma unroll
    for (int k = 0; k < SCAN_PER; k++) {
        int i = base + k;
        if (i < n) rowptr[i] = prefix + v[k];
    }
    if (tid == 255) blocksum[blockIdx.x] = part[255];
}

__global__ void scan_mid(int* __restrict__ blocksum, int nb) {
    if (threadIdx.x == 0) {
        int acc = 0;
        for (int b = 0; b < nb; b++) { int t = blocksum[b]; blocksum[b] = acc; acc += t; }
    }
}

// also fills row_of[i] = node for every CSR position i
__global__ __launch_bounds__(256) void scan_add(int* __restrict__ rowptr,
                                                int* __restrict__ cursor,
                                                const int* __restrict__ blocksum,
                                                const int* __restrict__ deg,
                                                int* __restrict__ row_of,
                                                int n, int total) {
    int base = blockIdx.x * SCAN_CHUNK + threadIdx.x * SCAN_PER;
    int off = blocksum[blockIdx.x];
#pragma unroll
    for (int k = 0; k < SCAN_PER; k++) {
        int j = base + k;
        if (j < n) {
            int r = rowptr[j] + off;
            rowptr[j] = r; cursor[j] = r;
            int dg = deg[j];
            for (int t = 0; t < dg; t++) row_of[r + t] = j;
        }
    }
    if (blockIdx.x == 0 && threadIdx.x == 0) rowptr[n] = total;
}

// scatter: one packed 8B random store per edge: {src, edge_id}
__global__ void scatter_kernel(const int* __restrict__ src, const int* __restrict__ dst,
                               int* __restrict__ cursor, int2* __restrict__ csr_se,
                               int E_, int n) {
    int e = blockIdx.x * blockDim.x + threadIdx.x;
    if (e >= E_ + n) return;
    int s, d;
    if (e < E_) { s = src[e]; d = dst[e]; } else { s = d = e - E_; }
    int i = atomicAdd(&cursor[d], 1);
    csr_se[i] = make_int2(s, e);
}

// ---------------------------------------------------------------------------
// graph boundaries in sorted batch: gstart[g] = lower_bound(batch, g)
__global__ void bounds_kernel(const int* __restrict__ batch, int* __restrict__ gstart, int n) {
    int g = threadIdx.x;
    if (g > 64) return;
    if (g == 64) { gstart[64] = n; return; }
    int lo = 0, hi = n;
    while (lo < hi) {
        int mid = (lo + hi) >> 1;
        if (batch[mid] < g) lo = mid + 1; else hi = mid;
    }
    gstart[g] = lo;
}

// ---------------------------------------------------------------------------
// xw = X @ W  (128x128) -> bf16-packed XW, plus per-head dots a_src/a_dst (f32)
__global__ __launch_bounds__(256) void gemm_att(const float* __restrict__ X,
                                                const float* __restrict__ W,
                                                const float* __restrict__ att_s,
                                                const float* __restrict__ att_d,
                                                unsigned short* __restrict__ XWb,
                                                float* __restrict__ a_s,
                                                float* __restrict__ a_d, int n) {
    __shared__ float Wl[128 * 128];
    __shared__ float Xt[128][32];   // [k][row]
    int tid = threadIdx.x;
    {
        const float4* Wv = (const float4*)W;
        float4* Wlv = (float4*)Wl;
#pragma unroll
        for (int i = 0; i < 16; i++) Wlv[tid + i * 256] = Wv[tid + i * 256];
    }
    int cg = tid & 31;   // cols cg*4 .. cg*4+3
    int rg = tid >> 5;   // rows rg*4 .. rg*4+3 (of 32)
    float4 as4 = *(const float4*)(att_s + cg * 4);
    float4 ad4 = *(const float4*)(att_d + cg * 4);

    for (int half = 0; half < 2; half++) {
        int rowbase = blockIdx.x * 64 + half * 32;
        {
            int r = tid & 31, kb = (tid >> 5) * 16;
            int row = rowbase + r;
            __syncthreads();
#pragma unroll
            for (int q = 0; q < 4; q++) {
                float4 v = make_float4(0.f, 0.f, 0.f, 0.f);
                if (row < n) v = *(const float4*)(X + (size_t)row * 128 + kb + q * 4);
                Xt[kb + q * 4 + 0][r] = v.x;
                Xt[kb + q * 4 + 1][r] = v.y;
                Xt[kb + q * 4 + 2][r] = v.z;
                Xt[kb + q * 4 + 3][r] = v.w;
            }
            __syncthreads();
        }
        float acc[4][4];
#pragma unroll
        for (int r = 0; r < 4; r++)
#pragma unroll
            for (int c = 0; c < 4; c++) acc[r][c] = 0.f;

#pragma unroll 8
        for (int k = 0; k < 128; k++) {
            float4 xv = *(const float4*)(&Xt[k][rg * 4]);
            float4 wv = *(const float4*)(&Wl[k * 128 + cg * 4]);
            acc[0][0] += xv.x * wv.x; acc[0][1] += xv.x * wv.y; acc[0][2] += xv.x * wv.z; acc[0][3] += xv.x * wv.w;
            acc[1][0] += xv.y * wv.x; acc[1][1] += xv.y * wv.y; acc[1][2] += xv.y * wv.z; acc[1][3] += xv.y * wv.w;
            acc[2][0] += xv.z * wv.x; acc[2][1] += xv.z * wv.y; acc[2][2] += xv.z * wv.z; acc[2][3] += xv.z * wv.w;
            acc[3][0] += xv.w * wv.x; acc[3][1] += xv.w * wv.y; acc[3][2] += xv.w * wv.z; acc[3][3] += xv.w * wv.w;
        }
#pragma unroll
        for (int r = 0; r < 4; r++) {
            int row = rowbase + rg * 4 + r;
            float ss = acc[r][0] * as4.x + acc[r][1] * as4.y + acc[r][2] * as4.z + acc[r][3] * as4.w;
            float sd = acc[r][0] * ad4.x + acc[r][1] * ad4.y + acc[r][2] * ad4.z + acc[r][3] * ad4.w;
            ss += __shfl_xor(ss, 1, 8); ss += __shfl_xor(ss, 2, 8); ss += __shfl_xor(ss, 4, 8);
            sd += __shfl_xor(sd, 1, 8); sd += __shfl_xor(sd, 2, 8); sd += __shfl_xor(sd, 4, 8);
            if (row < n) {
                ushort4 pk;
                pk.x = bf16rne(acc[r][0]);
                pk.y = bf16rne(acc[r][1]);
                pk.z = bf16rne(acc[r][2]);
                pk.w = bf16rne(acc[r][3]);
                *(ushort4*)(XWb + (size_t)row * 128 + cg * 4) = pk;
                if ((cg & 7) == 0) {
                    a_s[row * 4 + (cg >> 3)] = ss;
                    a_d[row * 4 + (cg >> 3)] = sd;
                }
            }
        }
    }
}

// ---------------------------------------------------------------------------
// Layer-1 alpha, position-indexed (sequential writes). Streams ea ONCE
// (random reads, but each ea row is exactly one 64B line -> pure permutation),
// computes edge-projection for BOTH layers; writes csr_alpha (L1) and aeb2.
__global__ __launch_bounds__(256) void alpha1_fused(
    const int2* __restrict__ csr_se, const int* __restrict__ row_of,
    const float* __restrict__ ea,
    const float* __restrict__ V1, const float* __restrict__ V2,
    const float* __restrict__ aes1, const float* __restrict__ aes2,
    const float* __restrict__ a_s, const float* __restrict__ a_d,
    float* __restrict__ csr_alpha, float* __restrict__ aeb2, int E_, int EN_) {
    __shared__ float V1l[64], V2l[64], a1l[4], a2l[4];
    int tid = threadIdx.x;
    if (tid < 64) { V1l[tid] = V1[tid]; V2l[tid] = V2[tid]; }
    if (tid < 4) { a1l[tid] = aes1[tid]; a2l[tid] = aes2[tid]; }
    __syncthreads();
    int i = blockIdx.x * 256 + tid;
    if (i >= EN_) return;
    int2 se = csr_se[i];
    int s = se.x, e = se.y, d = row_of[i];
    float ae1[4], ae2[4];
    if (e < E_) {
#pragma unroll
        for (int h = 0; h < 4; h++) { ae1[h] = 0.f; ae2[h] = 0.f; }
        const float4* er = (const float4*)(ea + (size_t)e * 16);
#pragma unroll
        for (int q = 0; q < 4; q++) {
            float4 v = er[q];
#pragma unroll
            for (int h = 0; h < 4; h++) {
                ae1[h] += v.x * V1l[(q * 4 + 0) * 4 + h] + v.y * V1l[(q * 4 + 1) * 4 + h] +
                          v.z * V1l[(q * 4 + 2) * 4 + h] + v.w * V1l[(q * 4 + 3) * 4 + h];
                ae2[h] += v.x * V2l[(q * 4 + 0) * 4 + h] + v.y * V2l[(q * 4 + 1) * 4 + h] +
                          v.z * V2l[(q * 4 + 2) * 4 + h] + v.w * V2l[(q * 4 + 3) * 4 + h];
            }
        }
    } else {
#pragma unroll
        for (int h = 0; h < 4; h++) { ae1[h] = a1l[h]; ae2[h] = a2l[h]; }
    }
    float4 asv = *(const float4*)(a_s + (size_t)s * 4);
    float4 adv = *(const float4*)(a_d + (size_t)d * 4);
    float o0 = asv.x + adv.x + ae1[0];
    float o1 = asv.y + adv.y + ae1[1];
    float o2 = asv.z + adv.z + ae1[2];
    float o3 = asv.w + adv.w + ae1[3];
    o0 = o0 > 0.f ? o0 : NEG_SLOPE * o0;
    o1 = o1 > 0.f ? o1 : NEG_SLOPE * o1;
    o2 = o2 > 0.f ? o2 : NEG_SLOPE * o2;
    o3 = o3 > 0.f ? o3 : NEG_SLOPE * o3;
    *(float4*)(csr_alpha + (size_t)i * 4) = make_float4(o0, o1, o2, o3);
    *(float4*)(aeb2 + (size_t)i * 4) = make_float4(ae2[0], ae2[1], ae2[2], ae2[3]);
}

// ---------------------------------------------------------------------------
// Layer-2 alpha: pure streaming (no ea access), sequential in/out.
__global__ __launch_bounds__(256) void alpha2_kernel(
    const int2* __restrict__ csr_se, const int* __restrict__ row_of,
    const float* __restrict__ aeb2,
    const float* __restrict__ a_s, const float* __restrict__ a_d,
    float* __restrict__ csr_alpha, int EN_) {
    int i = blockIdx.x * 256 + threadIdx.x;
    if (i >= EN_) return;
    int s = csr_se[i].x, d = row_of[i];
    float4 ae = *(const float4*)(aeb2 + (size_t)i * 4);
    float4 asv = *(const float4*)(a_s + (size_t)s * 4);
    float4 adv = *(const float4*)(a_d + (size_t)d * 4);
    float o0 = asv.x + adv.x + ae.x;
    float o1 = asv.y + adv.y + ae.y;
    float o2 = asv.z + adv.z + ae.z;
    float o3 = asv.w + adv.w + ae.w;
    o0 = o0 > 0.f ? o0 : NEG_SLOPE * o0;
    o1 = o1 > 0.f ? o1 : NEG_SLOPE * o1;
    o2 = o2 > 0.f ? o2 : NEG_SLOPE * o2;
    o3 = o3 > 0.f ? o3 : NEG_SLOPE * o3;
    *(float4*)(csr_alpha + (size_t)i * 4) = make_float4(o0, o1, o2, o3);
}

// ---------------------------------------------------------------------------
// wave-cooperative segment softmax + bf16 gather; alphas are O(1) so exp
// without max-shift is overflow-safe and softmax-identical.
// lane = (h = lane>>4, j = lane&15); 16-edge chunks; w/src broadcast by shuffle.
// mode 1: fused bias+relu epilogue (layer 1); mode 0: plain write (layer 2).
__global__ __launch_bounds__(256) void dst_aggregate(
    const int* __restrict__ rowptr, const int2* __restrict__ csr_se,
    const float* __restrict__ csr_alpha, const unsigned int* __restrict__ XW,
    const float* __restrict__ bias, float* __restrict__ OUT, int n, int mode) {
    int wv = threadIdx.x >> 6, lane = threadIdx.x & 63;
    int d = blockIdx.x * 4 + wv;
    if (d >= n) return;
    int h = lane >> 4;    // own head
    int j = lane & 15;    // edge slot within chunk / channel-pair index
    int beg = rowptr[d], end = rowptr[d + 1];
    int gb = lane & 48;   // group base for w broadcast
    const unsigned int dwoff = h * 16 + j;   // dword index within 64-dword row

    float2 acc = make_float2(0.f, 0.f);
    float den = 0.f;

    int i = beg;
    for (; i + 16 <= end; i += 16) {
        float w = __expf(csr_alpha[(size_t)(i + j) * 4 + h]);
        int sreg = csr_se[i + j].x;
        den += w;
#pragma unroll
        for (int k = 0; k < 16; k++) {
            int s = __shfl(sreg, k);
            float wk = __shfl(w, gb | k);
            unsigned int v = XW[(size_t)s * 64 + dwoff];
            acc.x += wk * __uint_as_float(v << 16);
            acc.y += wk * __uint_as_float(v & 0xffff0000u);
        }
    }
    int cnt = end - i;
    if (cnt > 0) {
        float w = 0.f; int sreg = 0;
        if (j < cnt) {
            w = __expf(csr_alpha[(size_t)(i + j) * 4 + h]);
            sreg = csr_se[i + j].x;
        }
        den += w;
        for (int k = 0; k < cnt; k++) {
            int s = __shfl(sreg, k);
            float wk = __shfl(w, gb | k);
            unsigned int v = XW[(size_t)s * 64 + dwoff];
            acc.x += wk * __uint_as_float(v << 16);
            acc.y += wk * __uint_as_float(v & 0xffff0000u);
        }
    }
    den += __shfl_xor(den, 1);
    den += __shfl_xor(den, 2);
    den += __shfl_xor(den, 4);
    den += __shfl_xor(den, 8);
    float inv = 1.f / (den + 1e-16f);
    int c = h * 32 + j * 2;
    float o0 = acc.x * inv, o1 = acc.y * inv;
    if (mode == 1) {
        o0 = fmaxf(o0 + bias[c], 0.f);
        o1 = fmaxf(o1 + bias[c + 1], 0.f);
    }
    *(float2*)(OUT + (size_t)d * 128 + c) = make_float2(o0, o1);
}

// ---------------------------------------------------------------------------
// pooled[g,c] = sum over nodes of graph g of head-mean; one block per (g,split)
#define POOL_SPLITS 8
__global__ __launch_bounds__(256) void pool_kernel(const float* __restrict__ B,
                                                   const int* __restrict__ gstart,
                                                   float* __restrict__ pooled) {
    int g = blockIdx.x / POOL_SPLITS, sp = blockIdx.x % POOL_SPLITS;
    int lo = gstart[g], hi = gstart[g + 1];
    int cnt = hi - lo;
    int per = (cnt + POOL_SPLITS - 1) / POOL_SPLITS;
    int s0 = lo + sp * per;
    int s1 = min(s0 + per, hi);
    int c = threadIdx.x & 31, rl = threadIdx.x >> 5;
    float acc = 0.f;
    for (int node = s0 + rl; node < s1; node += 8) {
        const float* r = B + (size_t)node * 128;
        acc += 0.25f * (r[c] + r[c + 32] + r[c + 64] + r[c + 96]);
    }
    __shared__ float red[8][32];
    red[rl][c] = acc;
    __syncthreads();
    if (threadIdx.x < 32) {
        float s = 0.f;
#pragma unroll
        for (int i = 0; i < 8; i++) s += red[i][threadIdx.x];
        atomicAdd(&pooled[g * 32 + threadIdx.x], s);
    }
}

__global__ void mlp_kernel(const float* __restrict__ pooled, const int* __restrict__ gstart,
                           const float* __restrict__ b2,
                           const float* __restrict__ W3, const float* __restrict__ b3,
                           const float* __restrict__ W4, const float* __restrict__ b4,
                           float* __restrict__ out) {
    int g = blockIdx.x;
    int c = threadIdx.x;
    __shared__ float pm[32];
    __shared__ float t[32];
    int cnt = gstart[g + 1] - gstart[g];
    if (c < 32) {
        float m = 0.f;
        if (cnt > 0) m = pooled[g * 32 + c] / (float)cnt + b2[c];
        pm[c] = m;
    }
    __syncthreads();
    if (c < 32) {
        float s = b3[c];
        for (int k = 0; k < 32; k++) s += pm[k] * W3[k * 32 + c];
        t[c] = fmaxf(s, 0.f);
    }
    __syncthreads();
    if (c < 2) {
        float o = b4[c];
        for (int k = 0; k < 32; k++) o += t[k] * W4[k * 2 + c];
        out[g * 2 + c] = o;
    }
}

// ---------------------------------------------------------------------------
extern "C" void kernel_launch(void* const* d_in, const int* in_sizes, int n_in,
                              void* d_out, int out_size, void* d_ws, size_t ws_size,
                              hipStream_t stream) {
    const float* x    = (const float*)d_in[0];
    const int*   eidx = (const int*)d_in[1];
    const float* ea   = (const float*)d_in[2];
    const int*   batch= (const int*)d_in[3];
    const float* W1   = (const float*)d_in[4];
    const float* as1  = (const float*)d_in[5];
    const float* ad1  = (const float*)d_in[6];
    const float* We1  = (const float*)d_in[7];
    const float* ate1 = (const float*)d_in[8];
    const float* b1   = (const float*)d_in[9];
    const float* W2   = (const float*)d_in[10];
    const float* as2  = (const float*)d_in[11];
    const float* ad2  = (const float*)d_in[12];
    const float* We2  = (const float*)d_in[13];
    const float* ate2 = (const float*)d_in[14];
    const float* b2   = (const float*)d_in[15];
    const float* W3   = (const float*)d_in[16];
    const float* b3   = (const float*)d_in[17];
    const float* W4   = (const float*)d_in[18];
    const float* b4   = (const float*)d_in[19];

    const int N_ = in_sizes[0] / 128;
    const int E_ = in_sizes[1] / 2;
    const int EN = E_ + N_;
    const int* srcp = eidx;
    const int* dstp = eidx + E_;

    char* w = (char*)d_ws;
    size_t off = 0;
    auto alloc = [&](size_t bytes) -> void* {
        void* p = w + off;
        off = (off + bytes + 255) & ~(size_t)255;
        return p;
    };
    unsigned short* A = (unsigned short*)alloc((size_t)N_ * 128 * 2);  // bf16 XW
    float* Bb        = (float*)alloc((size_t)N_ * 128 * 4);
    float* csr_alpha = (float*)alloc((size_t)EN * 16);
    float* aeb2      = (float*)alloc((size_t)EN * 16);
    int2*  csr_se    = (int2*)alloc((size_t)EN * 8);
    int*   row_of    = (int*)alloc((size_t)EN * 4);
    int*   rowptr    = (int*)alloc((size_t)(N_ + 1) * 4);
    int*   cursor    = (int*)alloc((size_t)N_ * 4);
    int*   deg       = (int*)alloc((size_t)N_ * 4);
    int*   blocksum  = (int*)alloc(((size_t)N_ / SCAN_CHUNK + 2) * 4);
    float* a_s       = (float*)alloc((size_t)N_ * 16);
    float* a_d       = (float*)alloc((size_t)N_ * 16);
    float* ea_sums   = (float*)alloc(64);
    float* V1        = (float*)alloc(256);
    float* V2        = (float*)alloc(256);
    float* aes1      = (float*)alloc(16);
    float* aes2      = (float*)alloc(16);
    float* pooled    = (float*)alloc(64 * 32 * 4);
    int*   gstart    = (int*)alloc(65 * 4);

    hipMemsetAsync(deg, 0, (size_t)N_ * 4, stream);
    hipMemsetAsync(ea_sums, 0, 64, stream);
    hipMemsetAsync(pooled, 0, 64 * 32 * 4, stream);

    int ebk = (EN + 255) / 256;
    int nsb = (N_ + SCAN_CHUNK - 1) / SCAN_CHUNK;

    ea_colsum<<<1024, 256, 0, stream>>>(ea, ea_sums, E_);
    deg_kernel<<<ebk, 256, 0, stream>>>(dstp, deg, E_, N_);
    scan_part<<<nsb, 256, 0, stream>>>(deg, rowptr, blocksum, N_);
    scan_mid<<<1, 64, 0, stream>>>(blocksum, nsb);
    scan_add<<<nsb, 256, 0, stream>>>(rowptr, cursor, blocksum, deg, row_of, N_, EN);
    scatter_kernel<<<ebk, 256, 0, stream>>>(srcp, dstp, cursor, csr_se, E_, N_);
    prep_kernel<<<1, 128, 0, stream>>>(We1, ate1, We2, ate2, ea_sums, 1.0f / (float)E_,
                                       V1, V2, aes1, aes2);
    bounds_kernel<<<1, 128, 0, stream>>>(batch, gstart, N_);

    // ---- layer 1 ----
    gemm_att<<<(N_ + 63) / 64, 256, 0, stream>>>(x, W1, as1, ad1, A, a_s, a_d, N_);
    alpha1_fused<<<ebk, 256, 0, stream>>>(csr_se, row_of, ea, V1, V2, aes1, aes2,
                                          a_s, a_d, csr_alpha, aeb2, E_, EN);
    dst_aggregate<<<(N_ + 3) / 4, 256, 0, stream>>>(rowptr, csr_se, csr_alpha,
                                                    (const unsigned int*)A, b1, Bb, N_, 1);

    // ---- layer 2 ----
    gemm_att<<<(N_ + 63) / 64, 256, 0, stream>>>(Bb, W2, as2, ad2, A, a_s, a_d, N_);
    alpha2_kernel<<<ebk, 256, 0, stream>>>(csr_se, row_of, aeb2, a_s, a_d, csr_alpha, EN);
    dst_aggregate<<<(N_ + 3) / 4, 256, 0, stream>>>(rowptr, csr_se, csr_alpha,
                                                    (const unsigned int*)A, b2, Bb, N_, 0);
    pool_kernel<<<64 * POOL_SPLITS, 256, 0, stream>>>(Bb, gstart, pooled);

    // ---- graph MLP ----
    mlp_kernel<<<64, 64, 0, stream>>>(pooled, gstart, b2, W3, b3, W4, b4, (float*)d_out);
}

// Round 7
// 309.517 us; speedup vs baseline: 3.0704x; 1.2052x over previous
//
#include <hip/hip_runtime.h>
#include <hip/hip_bf16.h>

#define NEG_SLOPE 0.2f
#define BINB 512
#define BIN_CHUNK 8192
#define MAXBKT 2048

__device__ __forceinline__ unsigned short bf16rne(float x) {
    unsigned int u = __float_as_uint(x);
    u += 0x7fffu + ((u >> 16) & 1u);
    return (unsigned short)(u >> 16);
}

// ---------------------------------------------------------------------------
__global__ __launch_bounds__(256) void ea_colsum(const float* __restrict__ ea,
                                                 float* __restrict__ sums, int E_) {
    int j = threadIdx.x & 15, rl = threadIdx.x >> 4;
    float acc = 0.f;
    for (long long r = (long long)blockIdx.x * 16 + rl; r < E_; r += (long long)gridDim.x * 16)
        acc += ea[r * 16 + j];
    __shared__ float red[256];
    red[rl * 16 + j] = acc;
    __syncthreads();
    if (threadIdx.x < 16) {
        float s = 0.f;
#pragma unroll
        for (int i = 0; i < 16; i++) s += red[i * 16 + threadIdx.x];
        atomicAdd(&sums[threadIdx.x], s);
    }
}

// ---------------------------------------------------------------------------
__global__ void prep_kernel(const float* __restrict__ We1, const float* __restrict__ ate1,
                            const float* __restrict__ We2, const float* __restrict__ ate2,
                            const float* __restrict__ ea_sums, float invE,
                            float* __restrict__ V1, float* __restrict__ V2,
                            float* __restrict__ aes1, float* __restrict__ aes2) {
    int tid = threadIdx.x;
    __shared__ float V1s[64], V2s[64];
    if (tid < 64) {
        int dd = tid >> 2, h = tid & 3;
        float s = 0.f;
        for (int c = 0; c < 32; c++) s += We1[dd * 128 + h * 32 + c] * ate1[h * 32 + c];
        V1[dd * 4 + h] = s; V1s[dd * 4 + h] = s;
    } else if (tid < 128) {
        int t = tid - 64, dd = t >> 2, h = t & 3;
        float s = 0.f;
        for (int c = 0; c < 32; c++) s += We2[dd * 128 + h * 32 + c] * ate2[h * 32 + c];
        V2[dd * 4 + h] = s; V2s[dd * 4 + h] = s;
    }
    __syncthreads();
    if (tid < 4) {
        float s = 0.f;
        for (int dd = 0; dd < 16; dd++) s += ea_sums[dd] * invE * V1s[dd * 4 + tid];
        aes1[tid] = s;
    } else if (tid >= 64 && tid < 68) {
        int h = tid - 64;
        float s = 0.f;
        for (int dd = 0; dd < 16; dd++) s += ea_sums[dd] * invE * V2s[dd * 4 + h];
        aes2[h] = s;
    }
}

// ---------------------------------------------------------------------------
// Phase 1: per-block bucket histogram; atomicAdd reserves this block's base.
__global__ __launch_bounds__(256) void bin_count(const int* __restrict__ dst,
                                                 int* __restrict__ bucket_cnt,
                                                 int* __restrict__ blockbase,
                                                 int E_, int EN_, int npb) {
    __shared__ int hist[BINB];
    int tid = threadIdx.x;
    for (int i = tid; i < BINB; i += 256) hist[i] = 0;
    __syncthreads();
    int base = blockIdx.x * BIN_CHUNK;
    int lim = min(base + BIN_CHUNK, EN_);
    for (int e = base + tid; e < lim; e += 256) {
        int d = (e < E_) ? dst[e] : e - E_;
        atomicAdd(&hist[d / npb], 1);
    }
    __syncthreads();
    for (int b = tid; b < BINB; b += 256) {
        int c = hist[b];
        blockbase[blockIdx.x * BINB + b] = (c > 0) ? atomicAdd(&bucket_cnt[b], c) : 0;
    }
}

// Phase 2: exclusive scan of bucket counts -> bucket offsets (= rowptr at
// bucket boundaries, since buckets partition the dst range).
__global__ __launch_bounds__(512) void bucket_scan(const int* __restrict__ bucket_cnt,
                                                   int* __restrict__ bucket_off,
                                                   int* __restrict__ rowptr, int n, int total) {
    __shared__ int tmp[BINB];
    int t = threadIdx.x;
    tmp[t] = bucket_cnt[t];
    __syncthreads();
    for (int off = 1; off < BINB; off <<= 1) {
        int v = (t >= off) ? tmp[t - off] : 0;
        __syncthreads();
        tmp[t] += v;
        __syncthreads();
    }
    bucket_off[t] = (t == 0) ? 0 : tmp[t - 1];
    if (t == 0) rowptr[n] = total;
}

// Phase 3: scatter into bucket regions; each (block,bucket) chunk lands
// contiguously -> full-line, single-writer stores.
__global__ __launch_bounds__(256) void bin_scatter(const int* __restrict__ src,
                                                   const int* __restrict__ dst,
                                                   const int* __restrict__ bucket_off,
                                                   const int* __restrict__ blockbase,
                                                   int2* __restrict__ bin_se,
                                                   int* __restrict__ bin_dst,
                                                   int E_, int EN_, int npb) {
    __shared__ int hist[BINB];
    int tid = threadIdx.x;
    for (int i = tid; i < BINB; i += 256) hist[i] = 0;
    __syncthreads();
    int base = blockIdx.x * BIN_CHUNK;
    int lim = min(base + BIN_CHUNK, EN_);
    for (int e = base + tid; e < lim; e += 256) {
        int s, d;
        if (e < E_) { s = src[e]; d = dst[e]; } else { s = d = e - E_; }
        int b = d / npb;
        int rank = atomicAdd(&hist[b], 1);
        int pos = bucket_off[b] + blockbase[blockIdx.x * BINB + b] + rank;
        bin_se[pos] = make_int2(s, e);
        bin_dst[pos] = d;
    }
}

// Phase 4: one block per bucket. Derives rowptr for its 98-node range from an
// LDS histogram (replaces deg_kernel + global scan), then scatters records
// into its contiguous CSR region (block-local, full-line writes).
__global__ __launch_bounds__(256) void csr_build(const int* __restrict__ bucket_off,
                                                 const int2* __restrict__ bin_se,
                                                 const int* __restrict__ bin_dst,
                                                 int2* __restrict__ csr_se,
                                                 int* __restrict__ row_of,
                                                 int* __restrict__ rowptr,
                                                 int n, int EN_, int npb) {
    __shared__ int dstl[MAXBKT];
    __shared__ int cnts[256];
    int b = blockIdx.x;
    int tid = threadIdx.x;
    int nb = b * npb;
    int nn = min(npb, n - nb);
    if (nn <= 0) return;
    int off0 = bucket_off[b];
    int off1 = (b == BINB - 1) ? EN_ : bucket_off[b + 1];
    int cnt = min(off1 - off0, MAXBKT);
    cnts[tid] = 0;
    __syncthreads();
    for (int i = tid; i < cnt; i += 256) {
        int d = bin_dst[off0 + i];
        dstl[i] = d;
        atomicAdd(&cnts[d - nb], 1);
    }
    __syncthreads();
    for (int off = 1; off < 256; off <<= 1) {
        int v = (tid >= off) ? cnts[tid - off] : 0;
        __syncthreads();
        cnts[tid] += v;
        __syncthreads();
    }
    int excl = (tid == 0) ? 0 : cnts[tid - 1];
    __syncthreads();
    cnts[tid] = off0 + excl;           // per-node global cursor
    if (tid < nn) rowptr[nb + tid] = off0 + excl;
    __syncthreads();
    for (int i = tid; i < cnt; i += 256) {
        int d = dstl[i];
        int pos = atomicAdd(&cnts[d - nb], 1);
        csr_se[pos] = bin_se[off0 + i];
        row_of[pos] = d;
    }
}

// ---------------------------------------------------------------------------
__global__ void bounds_kernel(const int* __restrict__ batch, int* __restrict__ gstart, int n) {
    int g = threadIdx.x;
    if (g > 64) return;
    if (g == 64) { gstart[64] = n; return; }
    int lo = 0, hi = n;
    while (lo < hi) {
        int mid = (lo + hi) >> 1;
        if (batch[mid] < g) lo = mid + 1; else hi = mid;
    }
    gstart[g] = lo;
}

// ---------------------------------------------------------------------------
// xw = X @ W  (128x128) -> bf16-packed XW, plus per-head dots a_src/a_dst (f32)
__global__ __launch_bounds__(256) void gemm_att(const float* __restrict__ X,
                                                const float* __restrict__ W,
                                                const float* __restrict__ att_s,
                                                const float* __restrict__ att_d,
                                                unsigned short* __restrict__ XWb,
                                                float* __restrict__ a_s,
                                                float* __restrict__ a_d, int n) {
    __shared__ float Wl[128 * 128];
    __shared__ float Xt[128][32];   // [k][row]
    int tid = threadIdx.x;
    {
        const float4* Wv = (const float4*)W;
        float4* Wlv = (float4*)Wl;
#pragma unroll
        for (int i = 0; i < 16; i++) Wlv[tid + i * 256] = Wv[tid + i * 256];
    }
    int cg = tid & 31;
    int rg = tid >> 5;
    float4 as4 = *(const float4*)(att_s + cg * 4);
    float4 ad4 = *(const float4*)(att_d + cg * 4);

    for (int half = 0; half < 2; half++) {
        int rowbase = blockIdx.x * 64 + half * 32;
        {
            int r = tid & 31, kb = (tid >> 5) * 16;
            int row = rowbase + r;
            __syncthreads();
#pragma unroll
            for (int q = 0; q < 4; q++) {
                float4 v = make_float4(0.f, 0.f, 0.f, 0.f);
                if (row < n) v = *(const float4*)(X + (size_t)row * 128 + kb + q * 4);
                Xt[kb + q * 4 + 0][r] = v.x;
                Xt[kb + q * 4 + 1][r] = v.y;
                Xt[kb + q * 4 + 2][r] = v.z;
                Xt[kb + q * 4 + 3][r] = v.w;
            }
            __syncthreads();
        }
        float acc[4][4];
#pragma unroll
        for (int r = 0; r < 4; r++)
#pragma unroll
            for (int c = 0; c < 4; c++) acc[r][c] = 0.f;

#pragma unroll 8
        for (int k = 0; k < 128; k++) {
            float4 xv = *(const float4*)(&Xt[k][rg * 4]);
            float4 wv = *(const float4*)(&Wl[k * 128 + cg * 4]);
            acc[0][0] += xv.x * wv.x; acc[0][1] += xv.x * wv.y; acc[0][2] += xv.x * wv.z; acc[0][3] += xv.x * wv.w;
            acc[1][0] += xv.y * wv.x; acc[1][1] += xv.y * wv.y; acc[1][2] += xv.y * wv.z; acc[1][3] += xv.y * wv.w;
            acc[2][0] += xv.z * wv.x; acc[2][1] += xv.z * wv.y; acc[2][2] += xv.z * wv.z; acc[2][3] += xv.z * wv.w;
            acc[3][0] += xv.w * wv.x; acc[3][1] += xv.w * wv.y; acc[3][2] += xv.w * wv.z; acc[3][3] += xv.w * wv.w;
        }
#pragma unroll
        for (int r = 0; r < 4; r++) {
            int row = rowbase + rg * 4 + r;
            float ss = acc[r][0] * as4.x + acc[r][1] * as4.y + acc[r][2] * as4.z + acc[r][3] * as4.w;
            float sd = acc[r][0] * ad4.x + acc[r][1] * ad4.y + acc[r][2] * ad4.z + acc[r][3] * ad4.w;
            ss += __shfl_xor(ss, 1, 8); ss += __shfl_xor(ss, 2, 8); ss += __shfl_xor(ss, 4, 8);
            sd += __shfl_xor(sd, 1, 8); sd += __shfl_xor(sd, 2, 8); sd += __shfl_xor(sd, 4, 8);
            if (row < n) {
                ushort4 pk;
                pk.x = bf16rne(acc[r][0]);
                pk.y = bf16rne(acc[r][1]);
                pk.z = bf16rne(acc[r][2]);
                pk.w = bf16rne(acc[r][3]);
                *(ushort4*)(XWb + (size_t)row * 128 + cg * 4) = pk;
                if ((cg & 7) == 0) {
                    a_s[row * 4 + (cg >> 3)] = ss;
                    a_d[row * 4 + (cg >> 3)] = sd;
                }
            }
        }
    }
}

// ---------------------------------------------------------------------------
// Layer-1 alpha, position-indexed; streams ea once, computes both layers'
// edge projections; all writes sequential.
__global__ __launch_bounds__(256) void alpha1_fused(
    const int2* __restrict__ csr_se, const int* __restrict__ row_of,
    const float* __restrict__ ea,
    const float* __restrict__ V1, const float* __restrict__ V2,
    const float* __restrict__ aes1, const float* __restrict__ aes2,
    const float* __restrict__ a_s, const float* __restrict__ a_d,
    float* __restrict__ csr_alpha, float* __restrict__ aeb2, int E_, int EN_) {
    __shared__ float V1l[64], V2l[64], a1l[4], a2l[4];
    int tid = threadIdx.x;
    if (tid < 64) { V1l[tid] = V1[tid]; V2l[tid] = V2[tid]; }
    if (tid < 4) { a1l[tid] = aes1[tid]; a2l[tid] = aes2[tid]; }
    __syncthreads();
    int i = blockIdx.x * 256 + tid;
    if (i >= EN_) return;
    int2 se = csr_se[i];
    int s = se.x, e = se.y, d = row_of[i];
    float ae1[4], ae2[4];
    if (e < E_) {
#pragma unroll
        for (int h = 0; h < 4; h++) { ae1[h] = 0.f; ae2[h] = 0.f; }
        const float4* er = (const float4*)(ea + (size_t)e * 16);
#pragma unroll
        for (int q = 0; q < 4; q++) {
            float4 v = er[q];
#pragma unroll
            for (int h = 0; h < 4; h++) {
                ae1[h] += v.x * V1l[(q * 4 + 0) * 4 + h] + v.y * V1l[(q * 4 + 1) * 4 + h] +
                          v.z * V1l[(q * 4 + 2) * 4 + h] + v.w * V1l[(q * 4 + 3) * 4 + h];
                ae2[h] += v.x * V2l[(q * 4 + 0) * 4 + h] + v.y * V2l[(q * 4 + 1) * 4 + h] +
                          v.z * V2l[(q * 4 + 2) * 4 + h] + v.w * V2l[(q * 4 + 3) * 4 + h];
            }
        }
    } else {
#pragma unroll
        for (int h = 0; h < 4; h++) { ae1[h] = a1l[h]; ae2[h] = a2l[h]; }
    }
    float4 asv = *(const float4*)(a_s + (size_t)s * 4);
    float4 adv = *(const float4*)(a_d + (size_t)d * 4);
    float o0 = asv.x + adv.x + ae1[0];
    float o1 = asv.y + adv.y + ae1[1];
    float o2 = asv.z + adv.z + ae1[2];
    float o3 = asv.w + adv.w + ae1[3];
    o0 = o0 > 0.f ? o0 : NEG_SLOPE * o0;
    o1 = o1 > 0.f ? o1 : NEG_SLOPE * o1;
    o2 = o2 > 0.f ? o2 : NEG_SLOPE * o2;
    o3 = o3 > 0.f ? o3 : NEG_SLOPE * o3;
    *(float4*)(csr_alpha + (size_t)i * 4) = make_float4(o0, o1, o2, o3);
    *(float4*)(aeb2 + (size_t)i * 4) = make_float4(ae2[0], ae2[1], ae2[2], ae2[3]);
}

// ---------------------------------------------------------------------------
__global__ __launch_bounds__(256) void alpha2_kernel(
    const int2* __restrict__ csr_se, const int* __restrict__ row_of,
    const float* __restrict__ aeb2,
    const float* __restrict__ a_s, const float* __restrict__ a_d,
    float* __restrict__ csr_alpha, int EN_) {
    int i = blockIdx.x * 256 + threadIdx.x;
    if (i >= EN_) return;
    int s = csr_se[i].x, d = row_of[i];
    float4 ae = *(const float4*)(aeb2 + (size_t)i * 4);
    float4 asv = *(const float4*)(a_s + (size_t)s * 4);
    float4 adv = *(const float4*)(a_d + (size_t)d * 4);
    float o0 = asv.x + adv.x + ae.x;
    float o1 = asv.y + adv.y + ae.y;
    float o2 = asv.z + adv.z + ae.z;
    float o3 = asv.w + adv.w + ae.w;
    o0 = o0 > 0.f ? o0 : NEG_SLOPE * o0;
    o1 = o1 > 0.f ? o1 : NEG_SLOPE * o1;
    o2 = o2 > 0.f ? o2 : NEG_SLOPE * o2;
    o3 = o3 > 0.f ? o3 : NEG_SLOPE * o3;
    *(float4*)(csr_alpha + (size_t)i * 4) = make_float4(o0, o1, o2, o3);
}

// ---------------------------------------------------------------------------
__global__ __launch_bounds__(256) void dst_aggregate(
    const int* __restrict__ rowptr, const int2* __restrict__ csr_se,
    const float* __restrict__ csr_alpha, const unsigned int* __restrict__ XW,
    const float* __restrict__ bias, float* __restrict__ OUT, int n, int mode) {
    int wv = threadIdx.x >> 6, lane = threadIdx.x & 63;
    int d = blockIdx.x * 4 + wv;
    if (d >= n) return;
    int h = lane >> 4;
    int j = lane & 15;
    int beg = rowptr[d], end = rowptr[d + 1];
    int gb = lane & 48;
    const unsigned int dwoff = h * 16 + j;

    float2 acc = make_float2(0.f, 0.f);
    float den = 0.f;

    int i = beg;
    for (; i + 16 <= end; i += 16) {
        float w = __expf(csr_alpha[(size_t)(i + j) * 4 + h]);
        int sreg = csr_se[i + j].x;
        den += w;
#pragma unroll
        for (int k = 0; k < 16; k++) {
            int s = __shfl(sreg, k);
            float wk = __shfl(w, gb | k);
            unsigned int v = XW[(size_t)s * 64 + dwoff];
            acc.x += wk * __uint_as_float(v << 16);
            acc.y += wk * __uint_as_float(v & 0xffff0000u);
        }
    }
    int cnt = end - i;
    if (cnt > 0) {
        float w = 0.f; int sreg = 0;
        if (j < cnt) {
            w = __expf(csr_alpha[(size_t)(i + j) * 4 + h]);
            sreg = csr_se[i + j].x;
        }
        den += w;
        for (int k = 0; k < cnt; k++) {
            int s = __shfl(sreg, k);
            float wk = __shfl(w, gb | k);
            unsigned int v = XW[(size_t)s * 64 + dwoff];
            acc.x += wk * __uint_as_float(v << 16);
            acc.y += wk * __uint_as_float(v & 0xffff0000u);
        }
    }
    den += __shfl_xor(den, 1);
    den += __shfl_xor(den, 2);
    den += __shfl_xor(den, 4);
    den += __shfl_xor(den, 8);
    float inv = 1.f / (den + 1e-16f);
    int c = h * 32 + j * 2;
    float o0 = acc.x * inv, o1 = acc.y * inv;
    if (mode == 1) {
        o0 = fmaxf(o0 + bias[c], 0.f);
        o1 = fmaxf(o1 + bias[c + 1], 0.f);
    }
    *(float2*)(OUT + (size_t)d * 128 + c) = make_float2(o0, o1);
}

// ---------------------------------------------------------------------------
#define POOL_SPLITS 8
__global__ __launch_bounds__(256) void pool_kernel(const float* __restrict__ B,
                                                   const int* __restrict__ gstart,
                                                   float* __restrict__ pooled) {
    int g = blockIdx.x / POOL_SPLITS, sp = blockIdx.x % POOL_SPLITS;
    int lo = gstart[g], hi = gstart[g + 1];
    int cnt = hi - lo;
    int per = (cnt + POOL_SPLITS - 1) / POOL_SPLITS;
    int s0 = lo + sp * per;
    int s1 = min(s0 + per, hi);
    int c = threadIdx.x & 31, rl = threadIdx.x >> 5;
    float acc = 0.f;
    for (int node = s0 + rl; node < s1; node += 8) {
        const float* r = B + (size_t)node * 128;
        acc += 0.25f * (r[c] + r[c + 32] + r[c + 64] + r[c + 96]);
    }
    __shared__ float red[8][32];
    red[rl][c] = acc;
    __syncthreads();
    if (threadIdx.x < 32) {
        float s = 0.f;
#pragma unroll
        for (int i = 0; i < 8; i++) s += red[i][threadIdx.x];
        atomicAdd(&pooled[g * 32 + threadIdx.x], s);
    }
}

__global__ void mlp_kernel(const float* __restrict__ pooled, const int* __restrict__ gstart,
                           const float* __restrict__ b2,
                           const float* __restrict__ W3, const float* __restrict__ b3,
                           const float* __restrict__ W4, const float* __restrict__ b4,
                           float* __restrict__ out) {
    int g = blockIdx.x;
    int c = threadIdx.x;
    __shared__ float pm[32];
    __shared__ float t[32];
    int cnt = gstart[g + 1] - gstart[g];
    if (c < 32) {
        float m = 0.f;
        if (cnt > 0) m = pooled[g * 32 + c] / (float)cnt + b2[c];
        pm[c] = m;
    }
    __syncthreads();
    if (c < 32) {
        float s = b3[c];
        for (int k = 0; k < 32; k++) s += pm[k] * W3[k * 32 + c];
        t[c] = fmaxf(s, 0.f);
    }
    __syncthreads();
    if (c < 2) {
        float o = b4[c];
        for (int k = 0; k < 32; k++) o += t[k] * W4[k * 2 + c];
        out[g * 2 + c] = o;
    }
}

// ---------------------------------------------------------------------------
extern "C" void kernel_launch(void* const* d_in, const int* in_sizes, int n_in,
                              void* d_out, int out_size, void* d_ws, size_t ws_size,
                              hipStream_t stream) {
    const float* x    = (const float*)d_in[0];
    const int*   eidx = (const int*)d_in[1];
    const float* ea   = (const float*)d_in[2];
    const int*   batch= (const int*)d_in[3];
    const float* W1   = (const float*)d_in[4];
    const float* as1  = (const float*)d_in[5];
    const float* ad1  = (const float*)d_in[6];
    const float* We1  = (const float*)d_in[7];
    const float* ate1 = (const float*)d_in[8];
    const float* b1   = (const float*)d_in[9];
    const float* W2   = (const float*)d_in[10];
    const float* as2  = (const float*)d_in[11];
    const float* ad2  = (const float*)d_in[12];
    const float* We2  = (const float*)d_in[13];
    const float* ate2 = (const float*)d_in[14];
    const float* b2   = (const float*)d_in[15];
    const float* W3   = (const float*)d_in[16];
    const float* b3   = (const float*)d_in[17];
    const float* W4   = (const float*)d_in[18];
    const float* b4   = (const float*)d_in[19];

    const int N_ = in_sizes[0] / 128;
    const int E_ = in_sizes[1] / 2;
    const int EN = E_ + N_;
    const int* srcp = eidx;
    const int* dstp = eidx + E_;
    const int npb = (N_ + BINB - 1) / BINB;       // nodes per bucket
    const int nbk = (EN + BIN_CHUNK - 1) / BIN_CHUNK;

    char* w = (char*)d_ws;
    size_t off = 0;
    auto alloc = [&](size_t bytes) -> void* {
        void* p = w + off;
        off = (off + bytes + 255) & ~(size_t)255;
        return p;
    };
    unsigned short* A = (unsigned short*)alloc((size_t)N_ * 128 * 2);  // bf16 XW
    float* Bb        = (float*)alloc((size_t)N_ * 128 * 4);
    float* csr_alpha = (float*)alloc((size_t)EN * 16);
    float* aeb2      = (float*)alloc((size_t)EN * 16);
    int2*  csr_se    = (int2*)alloc((size_t)EN * 8);
    int*   row_of    = (int*)alloc((size_t)EN * 4);
    int2*  bin_se    = (int2*)alloc((size_t)EN * 8);
    int*   bin_dst   = (int*)alloc((size_t)EN * 4);
    int*   rowptr    = (int*)alloc((size_t)(N_ + 1) * 4);
    int*   bucket_cnt= (int*)alloc(BINB * 4);
    int*   bucket_off= (int*)alloc(BINB * 4);
    int*   blockbase = (int*)alloc((size_t)nbk * BINB * 4);
    float* a_s       = (float*)alloc((size_t)N_ * 16);
    float* a_d       = (float*)alloc((size_t)N_ * 16);
    float* ea_sums   = (float*)alloc(64);
    float* V1        = (float*)alloc(256);
    float* V2        = (float*)alloc(256);
    float* aes1      = (float*)alloc(16);
    float* aes2      = (float*)alloc(16);
    float* pooled    = (float*)alloc(64 * 32 * 4);
    int*   gstart    = (int*)alloc(65 * 4);

    hipMemsetAsync(bucket_cnt, 0, BINB * 4, stream);
    hipMemsetAsync(ea_sums, 0, 64, stream);
    hipMemsetAsync(pooled, 0, 64 * 32 * 4, stream);

    int ebk = (EN + 255) / 256;

    ea_colsum<<<1024, 256, 0, stream>>>(ea, ea_sums, E_);
    bin_count<<<nbk, 256, 0, stream>>>(dstp, bucket_cnt, blockbase, E_, EN, npb);
    bucket_scan<<<1, BINB, 0, stream>>>(bucket_cnt, bucket_off, rowptr, N_, EN);
    bin_scatter<<<nbk, 256, 0, stream>>>(srcp, dstp, bucket_off, blockbase,
                                         bin_se, bin_dst, E_, EN, npb);
    csr_build<<<BINB, 256, 0, stream>>>(bucket_off, bin_se, bin_dst,
                                        csr_se, row_of, rowptr, N_, EN, npb);
    prep_kernel<<<1, 128, 0, stream>>>(We1, ate1, We2, ate2, ea_sums, 1.0f / (float)E_,
                                       V1, V2, aes1, aes2);
    bounds_kernel<<<1, 128, 0, stream>>>(batch, gstart, N_);

    // ---- layer 1 ----
    gemm_att<<<(N_ + 63) / 64, 256, 0, stream>>>(x, W1, as1, ad1, A, a_s, a_d, N_);
    alpha1_fused<<<ebk, 256, 0, stream>>>(csr_se, row_of, ea, V1, V2, aes1, aes2,
                                          a_s, a_d, csr_alpha, aeb2, E_, EN);
    dst_aggregate<<<(N_ + 3) / 4, 256, 0, stream>>>(rowptr, csr_se, csr_alpha,
                                                    (const unsigned int*)A, b1, Bb, N_, 1);

    // ---- layer 2 ----
    gemm_att<<<(N_ + 63) / 64, 256, 0, stream>>>(Bb, W2, as2, ad2, A, a_s, a_d, N_);
    alpha2_kernel<<<ebk, 256, 0, stream>>>(csr_se, row_of, aeb2, a_s, a_d, csr_alpha, EN);
    dst_aggregate<<<(N_ + 3) / 4, 256, 0, stream>>>(rowptr, csr_se, csr_alpha,
                                                    (const unsigned int*)A, b2, Bb, N_, 0);
    pool_kernel<<<64 * POOL_SPLITS, 256, 0, stream>>>(Bb, gstart, pooled);

    // ---- graph MLP ----
    mlp_kernel<<<64, 64, 0, stream>>>(pooled, gstart, b2, W3, b3, W4, b4, (float*)d_out);
}

// Round 8
// 289.284 us; speedup vs baseline: 3.2851x; 1.0699x over previous
//
#include <hip/hip_runtime.h>
#include <hip/hip_bf16.h>

#define NEG_SLOPE 0.2f
#define BINB 512
#define BIN_CHUNK 8192
#define MAXBKT 2048

typedef __attribute__((ext_vector_type(8))) short bf16x8;
typedef __attribute__((ext_vector_type(4))) float f32x4;

__device__ __forceinline__ unsigned short bf16rne(float x) {
    unsigned int u = __float_as_uint(x);
    u += 0x7fffu + ((u >> 16) & 1u);
    return (unsigned short)(u >> 16);
}
__device__ __forceinline__ unsigned int pk2bf16(float lo, float hi) {
    return ((unsigned int)bf16rne(hi) << 16) | bf16rne(lo);
}

// ---------------------------------------------------------------------------
__global__ __launch_bounds__(256) void ea_colsum(const float* __restrict__ ea,
                                                 float* __restrict__ sums, int E_) {
    int j = threadIdx.x & 15, rl = threadIdx.x >> 4;
    float acc = 0.f;
    for (long long r = (long long)blockIdx.x * 16 + rl; r < E_; r += (long long)gridDim.x * 16)
        acc += ea[r * 16 + j];
    __shared__ float red[256];
    red[rl * 16 + j] = acc;
    __syncthreads();
    if (threadIdx.x < 16) {
        float s = 0.f;
#pragma unroll
        for (int i = 0; i < 16; i++) s += red[i * 16 + threadIdx.x];
        atomicAdd(&sums[threadIdx.x], s);
    }
}

// ---------------------------------------------------------------------------
__global__ void prep_kernel(const float* __restrict__ We1, const float* __restrict__ ate1,
                            const float* __restrict__ We2, const float* __restrict__ ate2,
                            const float* __restrict__ ea_sums, float invE,
                            float* __restrict__ V1, float* __restrict__ V2,
                            float* __restrict__ aes1, float* __restrict__ aes2) {
    int tid = threadIdx.x;
    __shared__ float V1s[64], V2s[64];
    if (tid < 64) {
        int dd = tid >> 2, h = tid & 3;
        float s = 0.f;
        for (int c = 0; c < 32; c++) s += We1[dd * 128 + h * 32 + c] * ate1[h * 32 + c];
        V1[dd * 4 + h] = s; V1s[dd * 4 + h] = s;
    } else if (tid < 128) {
        int t = tid - 64, dd = t >> 2, h = t & 3;
        float s = 0.f;
        for (int c = 0; c < 32; c++) s += We2[dd * 128 + h * 32 + c] * ate2[h * 32 + c];
        V2[dd * 4 + h] = s; V2s[dd * 4 + h] = s;
    }
    __syncthreads();
    if (tid < 4) {
        float s = 0.f;
        for (int dd = 0; dd < 16; dd++) s += ea_sums[dd] * invE * V1s[dd * 4 + tid];
        aes1[tid] = s;
    } else if (tid >= 64 && tid < 68) {
        int h = tid - 64;
        float s = 0.f;
        for (int dd = 0; dd < 16; dd++) s += ea_sums[dd] * invE * V2s[dd * 4 + h];
        aes2[h] = s;
    }
}

// ---------------------------------------------------------------------------
__global__ __launch_bounds__(256) void bin_count(const int* __restrict__ dst,
                                                 int* __restrict__ bucket_cnt,
                                                 int* __restrict__ blockbase,
                                                 int E_, int EN_, int npb) {
    __shared__ int hist[BINB];
    int tid = threadIdx.x;
    for (int i = tid; i < BINB; i += 256) hist[i] = 0;
    __syncthreads();
    int base = blockIdx.x * BIN_CHUNK;
    int lim = min(base + BIN_CHUNK, EN_);
    for (int e = base + tid; e < lim; e += 256) {
        int d = (e < E_) ? dst[e] : e - E_;
        atomicAdd(&hist[d / npb], 1);
    }
    __syncthreads();
    for (int b = tid; b < BINB; b += 256) {
        int c = hist[b];
        blockbase[blockIdx.x * BINB + b] = (c > 0) ? atomicAdd(&bucket_cnt[b], c) : 0;
    }
}

__global__ __launch_bounds__(512) void bucket_scan(const int* __restrict__ bucket_cnt,
                                                   int* __restrict__ bucket_off,
                                                   int* __restrict__ rowptr, int n, int total) {
    __shared__ int tmp[BINB];
    int t = threadIdx.x;
    tmp[t] = bucket_cnt[t];
    __syncthreads();
    for (int off = 1; off < BINB; off <<= 1) {
        int v = (t >= off) ? tmp[t - off] : 0;
        __syncthreads();
        tmp[t] += v;
        __syncthreads();
    }
    bucket_off[t] = (t == 0) ? 0 : tmp[t - 1];
    if (t == 0) rowptr[n] = total;
}

__global__ __launch_bounds__(256) void bin_scatter(const int* __restrict__ src,
                                                   const int* __restrict__ dst,
                                                   const int* __restrict__ bucket_off,
                                                   const int* __restrict__ blockbase,
                                                   int2* __restrict__ bin_se,
                                                   int* __restrict__ bin_dst,
                                                   int E_, int EN_, int npb) {
    __shared__ int hist[BINB];
    int tid = threadIdx.x;
    for (int i = tid; i < BINB; i += 256) hist[i] = 0;
    __syncthreads();
    int base = blockIdx.x * BIN_CHUNK;
    int lim = min(base + BIN_CHUNK, EN_);
    for (int e = base + tid; e < lim; e += 256) {
        int s, d;
        if (e < E_) { s = src[e]; d = dst[e]; } else { s = d = e - E_; }
        int b = d / npb;
        int rank = atomicAdd(&hist[b], 1);
        int pos = bucket_off[b] + blockbase[blockIdx.x * BINB + b] + rank;
        bin_se[pos] = make_int2(s, e);
        bin_dst[pos] = d;
    }
}

__global__ __launch_bounds__(256) void csr_build(const int* __restrict__ bucket_off,
                                                 const int2* __restrict__ bin_se,
                                                 const int* __restrict__ bin_dst,
                                                 int2* __restrict__ csr_se,
                                                 int* __restrict__ row_of,
                                                 int* __restrict__ rowptr,
                                                 int n, int EN_, int npb) {
    __shared__ int dstl[MAXBKT];
    __shared__ int cnts[256];
    int b = blockIdx.x;
    int tid = threadIdx.x;
    int nb = b * npb;
    int nn = min(npb, n - nb);
    if (nn <= 0) return;
    int off0 = bucket_off[b];
    int off1 = (b == BINB - 1) ? EN_ : bucket_off[b + 1];
    int cnt = min(off1 - off0, MAXBKT);
    cnts[tid] = 0;
    __syncthreads();
    for (int i = tid; i < cnt; i += 256) {
        int d = bin_dst[off0 + i];
        dstl[i] = d;
        atomicAdd(&cnts[d - nb], 1);
    }
    __syncthreads();
    for (int off = 1; off < 256; off <<= 1) {
        int v = (tid >= off) ? cnts[tid - off] : 0;
        __syncthreads();
        cnts[tid] += v;
        __syncthreads();
    }
    int excl = (tid == 0) ? 0 : cnts[tid - 1];
    __syncthreads();
    cnts[tid] = off0 + excl;
    if (tid < nn) rowptr[nb + tid] = off0 + excl;
    __syncthreads();
    for (int i = tid; i < cnt; i += 256) {
        int d = dstl[i];
        int pos = atomicAdd(&cnts[d - nb], 1);
        csr_se[pos] = bin_se[off0 + i];
        row_of[pos] = d;
    }
}

// ---------------------------------------------------------------------------
__global__ void bounds_kernel(const int* __restrict__ batch, int* __restrict__ gstart, int n) {
    int g = threadIdx.x;
    if (g > 64) return;
    if (g == 64) { gstart[64] = n; return; }
    int lo = 0, hi = n;
    while (lo < hi) {
        int mid = (lo + hi) >> 1;
        if (batch[mid] < g) lo = mid + 1; else hi = mid;
    }
    gstart[g] = lo;
}

// ---------------------------------------------------------------------------
// MFMA GEMM: XW(bf16) = X @ W with per-head att dots.
// Block: 64 rows x 128 cols; 4 waves x 16 rows; K=128 via 4x mfma 16x16x32.
// W staged transposed Wt[n][k] bf16 (+8 pad): frag reads are ds_read_b128,
// 2-way bank aliasing only (free). C/D layout: col=lane&15, row=(lane>>4)*4+i.
template<bool BF16IN>
__global__ __launch_bounds__(256) void gemm_att_mfma(
    const void* __restrict__ Xin, const float* __restrict__ W,
    const float* __restrict__ att_s, const float* __restrict__ att_d,
    unsigned short* __restrict__ XWb, float* __restrict__ a_s,
    float* __restrict__ a_d, int n) {
    __shared__ unsigned short Wt[128][136];
    __shared__ unsigned short Xs[4][16][136];
    __shared__ float attsL[128], attdL[128];

    int tid = threadIdx.x;
    int w = tid >> 6, lane = tid & 63;
    int l15 = lane & 15, rgrp = lane >> 4;

    if (tid < 128) { attsL[tid] = att_s[tid]; attdL[tid] = att_d[tid]; }

    // stage Wt (transpose, pack 2 k's per u32)
    for (int idx = tid; idx < 8192; idx += 256) {
        int k2 = idx >> 7, nn = idx & 127;
        int k = k2 * 2;
        *(unsigned int*)&Wt[nn][k] = pk2bf16(W[k * 128 + nn], W[(k + 1) * 128 + nn]);
    }

    // stage this wave's 16 A-rows
    int r0 = blockIdx.x * 64 + w * 16;
    {
        int rr = lane >> 2;
        int row = r0 + rr;
        int c0 = (lane & 3) * 32;
        if (!BF16IN) {
            const float* Xf = (const float*)Xin;
#pragma unroll
            for (int q = 0; q < 8; q++) {
                int c = c0 + q * 4;
                float4 v = make_float4(0.f, 0.f, 0.f, 0.f);
                if (row < n) v = *(const float4*)(Xf + (size_t)row * 128 + c);
                uint2 p;
                p.x = pk2bf16(v.x, v.y);
                p.y = pk2bf16(v.z, v.w);
                *(uint2*)&Xs[w][rr][c] = p;
            }
        } else {
            const unsigned short* Xb = (const unsigned short*)Xin;
#pragma unroll
            for (int q = 0; q < 4; q++) {
                int c = c0 + q * 8;
                uint4 v = make_uint4(0u, 0u, 0u, 0u);
                if (row < n) v = *(const uint4*)(Xb + (size_t)row * 128 + c);
                *(uint4*)&Xs[w][rr][c] = v;
            }
        }
    }
    __syncthreads();

    f32x4 acc[8];
#pragma unroll
    for (int ct = 0; ct < 8; ct++) acc[ct] = (f32x4){0.f, 0.f, 0.f, 0.f};

#pragma unroll
    for (int kt = 0; kt < 4; kt++) {
        int k0 = kt * 32 + rgrp * 8;
        bf16x8 a = *(const bf16x8*)&Xs[w][l15][k0];
#pragma unroll
        for (int ct = 0; ct < 8; ct++) {
            bf16x8 b = *(const bf16x8*)&Wt[ct * 16 + l15][k0];
            acc[ct] = __builtin_amdgcn_mfma_f32_16x16x32_bf16(a, b, acc[ct], 0, 0, 0);
        }
    }

    // att dots: head h <- col tiles {2h, 2h+1}; reduce over the 16 lanes of l15
    float ar[8], br[8];
#pragma unroll
    for (int ct = 0; ct < 8; ct++) {
        ar[ct] = attsL[ct * 16 + l15];
        br[ct] = attdL[ct * 16 + l15];
    }
#pragma unroll
    for (int i = 0; i < 4; i++) {
        float ps[4], pd[4];
#pragma unroll
        for (int h = 0; h < 4; h++) {
            ps[h] = acc[2 * h][i] * ar[2 * h] + acc[2 * h + 1][i] * ar[2 * h + 1];
            pd[h] = acc[2 * h][i] * br[2 * h] + acc[2 * h + 1][i] * br[2 * h + 1];
        }
#pragma unroll
        for (int off = 1; off < 16; off <<= 1) {
#pragma unroll
            for (int h = 0; h < 4; h++) {
                ps[h] += __shfl_xor(ps[h], off);
                pd[h] += __shfl_xor(pd[h], off);
            }
        }
        if (l15 == 0) {
            int row = r0 + rgrp * 4 + i;
            if (row < n) {
                *(float4*)(a_s + (size_t)row * 4) = make_float4(ps[0], ps[1], ps[2], ps[3]);
                *(float4*)(a_d + (size_t)row * 4) = make_float4(pd[0], pd[1], pd[2], pd[3]);
            }
        }
    }

    // pack bf16 output via wave-private LDS staging (reuse Xs[w]) -> coalesced
    unsigned short* stage = &Xs[w][0][0];   // used flat as [16][128]
#pragma unroll
    for (int i = 0; i < 4; i++) {
        int row = rgrp * 4 + i;
#pragma unroll
        for (int ct = 0; ct < 8; ct++)
            stage[row * 128 + ct * 16 + l15] = bf16rne(acc[ct][i]);
    }
#pragma unroll
    for (int p = 0; p < 4; p++) {
        int fo = p * 1024 + lane * 16;       // byte offset in 4096
        int row = fo >> 8;
        int colb = fo & 255;
        uint4 v = *(const uint4*)((const char*)stage + fo);
        int grow = r0 + row;
        if (grow < n)
            *(uint4*)((char*)XWb + (size_t)grow * 256 + colb) = v;
    }
}

// ---------------------------------------------------------------------------
// Layer-1 alpha, position-indexed; streams ea once, computes both layers'
// edge projections; writes csr_alpha (L1 alpha) and aeb2 (L2 edge term).
__global__ __launch_bounds__(256) void alpha1_fused(
    const int2* __restrict__ csr_se, const int* __restrict__ row_of,
    const float* __restrict__ ea,
    const float* __restrict__ V1, const float* __restrict__ V2,
    const float* __restrict__ aes1, const float* __restrict__ aes2,
    const float* __restrict__ a_s, const float* __restrict__ a_d,
    float* __restrict__ csr_alpha, float* __restrict__ aeb2, int E_, int EN_) {
    __shared__ float V1l[64], V2l[64], a1l[4], a2l[4];
    int tid = threadIdx.x;
    if (tid < 64) { V1l[tid] = V1[tid]; V2l[tid] = V2[tid]; }
    if (tid < 4) { a1l[tid] = aes1[tid]; a2l[tid] = aes2[tid]; }
    __syncthreads();
    int i = blockIdx.x * 256 + tid;
    if (i >= EN_) return;
    int2 se = csr_se[i];
    int s = se.x, e = se.y, d = row_of[i];
    float ae1[4], ae2[4];
    if (e < E_) {
#pragma unroll
        for (int h = 0; h < 4; h++) { ae1[h] = 0.f; ae2[h] = 0.f; }
        const float4* er = (const float4*)(ea + (size_t)e * 16);
#pragma unroll
        for (int q = 0; q < 4; q++) {
            float4 v = er[q];
#pragma unroll
            for (int h = 0; h < 4; h++) {
                ae1[h] += v.x * V1l[(q * 4 + 0) * 4 + h] + v.y * V1l[(q * 4 + 1) * 4 + h] +
                          v.z * V1l[(q * 4 + 2) * 4 + h] + v.w * V1l[(q * 4 + 3) * 4 + h];
                ae2[h] += v.x * V2l[(q * 4 + 0) * 4 + h] + v.y * V2l[(q * 4 + 1) * 4 + h] +
                          v.z * V2l[(q * 4 + 2) * 4 + h] + v.w * V2l[(q * 4 + 3) * 4 + h];
            }
        }
    } else {
#pragma unroll
        for (int h = 0; h < 4; h++) { ae1[h] = a1l[h]; ae2[h] = a2l[h]; }
    }
    float4 asv = *(const float4*)(a_s + (size_t)s * 4);
    float4 adv = *(const float4*)(a_d + (size_t)d * 4);
    float o0 = asv.x + adv.x + ae1[0];
    float o1 = asv.y + adv.y + ae1[1];
    float o2 = asv.z + adv.z + ae1[2];
    float o3 = asv.w + adv.w + ae1[3];
    o0 = o0 > 0.f ? o0 : NEG_SLOPE * o0;
    o1 = o1 > 0.f ? o1 : NEG_SLOPE * o1;
    o2 = o2 > 0.f ? o2 : NEG_SLOPE * o2;
    o3 = o3 > 0.f ? o3 : NEG_SLOPE * o3;
    *(float4*)(csr_alpha + (size_t)i * 4) = make_float4(o0, o1, o2, o3);
    *(float4*)(aeb2 + (size_t)i * 4) = make_float4(ae2[0], ae2[1], ae2[2], ae2[3]);
}

// ---------------------------------------------------------------------------
// wave-cooperative segment softmax + bf16 gather.
// MODE 1 (layer 1): alpha precomputed (csr_alpha); out bf16 with bias+relu.
// MODE 0 (layer 2): alpha inline = a_s[s]+a_d[d]+aeb2[i] (kills alpha2 pass);
//                   out f32.
template<int MODE>
__global__ __launch_bounds__(256) void dst_aggregate(
    const int* __restrict__ rowptr, const int2* __restrict__ csr_se,
    const float* __restrict__ alpha_arr, const float* __restrict__ as2,
    const float* __restrict__ ad2, const unsigned int* __restrict__ XW,
    const float* __restrict__ bias, void* __restrict__ OUT, int n) {
    int wv = threadIdx.x >> 6, lane = threadIdx.x & 63;
    int d = blockIdx.x * 4 + wv;
    if (d >= n) return;
    int h = lane >> 4;
    int j = lane & 15;
    int beg = rowptr[d], end = rowptr[d + 1];
    int gb = lane & 48;
    const unsigned int dwoff = h * 16 + j;

    float advh = 0.f;
    if (MODE == 0) advh = ad2[(size_t)d * 4 + h];

    float2 acc = make_float2(0.f, 0.f);
    float den = 0.f;

    int i = beg;
    for (; i + 16 <= end; i += 16) {
        int sreg = csr_se[i + j].x;
        float w;
        if (MODE == 1) {
            w = __expf(alpha_arr[(size_t)(i + j) * 4 + h]);
        } else {
            float a = as2[(size_t)sreg * 4 + h] + advh + alpha_arr[(size_t)(i + j) * 4 + h];
            a = a > 0.f ? a : NEG_SLOPE * a;
            w = __expf(a);
        }
        den += w;
#pragma unroll
        for (int k = 0; k < 16; k++) {
            int s = __shfl(sreg, k);
            float wk = __shfl(w, gb | k);
            unsigned int v = XW[(size_t)s * 64 + dwoff];
            acc.x += wk * __uint_as_float(v << 16);
            acc.y += wk * __uint_as_float(v & 0xffff0000u);
        }
    }
    int cnt = end - i;
    if (cnt > 0) {
        float w = 0.f; int sreg = 0;
        if (j < cnt) {
            sreg = csr_se[i + j].x;
            if (MODE == 1) {
                w = __expf(alpha_arr[(size_t)(i + j) * 4 + h]);
            } else {
                float a = as2[(size_t)sreg * 4 + h] + advh + alpha_arr[(size_t)(i + j) * 4 + h];
                a = a > 0.f ? a : NEG_SLOPE * a;
                w = __expf(a);
            }
        }
        den += w;
        for (int k = 0; k < cnt; k++) {
            int s = __shfl(sreg, k);
            float wk = __shfl(w, gb | k);
            unsigned int v = XW[(size_t)s * 64 + dwoff];
            acc.x += wk * __uint_as_float(v << 16);
            acc.y += wk * __uint_as_float(v & 0xffff0000u);
        }
    }
    den += __shfl_xor(den, 1);
    den += __shfl_xor(den, 2);
    den += __shfl_xor(den, 4);
    den += __shfl_xor(den, 8);
    float inv = 1.f / (den + 1e-16f);
    int c = h * 32 + j * 2;
    float o0 = acc.x * inv, o1 = acc.y * inv;
    if (MODE == 1) {
        o0 = fmaxf(o0 + bias[c], 0.f);
        o1 = fmaxf(o1 + bias[c + 1], 0.f);
        ((unsigned int*)OUT)[(size_t)d * 64 + dwoff] = pk2bf16(o0, o1);
    } else {
        *(float2*)((float*)OUT + (size_t)d * 128 + c) = make_float2(o0, o1);
    }
}

// ---------------------------------------------------------------------------
#define POOL_SPLITS 8
__global__ __launch_bounds__(256) void pool_kernel(const float* __restrict__ B,
                                                   const int* __restrict__ gstart,
                                                   float* __restrict__ pooled) {
    int g = blockIdx.x / POOL_SPLITS, sp = blockIdx.x % POOL_SPLITS;
    int lo = gstart[g], hi = gstart[g + 1];
    int cnt = hi - lo;
    int per = (cnt + POOL_SPLITS - 1) / POOL_SPLITS;
    int s0 = lo + sp * per;
    int s1 = min(s0 + per, hi);
    int c = threadIdx.x & 31, rl = threadIdx.x >> 5;
    float acc = 0.f;
    for (int node = s0 + rl; node < s1; node += 8) {
        const float* r = B + (size_t)node * 128;
        acc += 0.25f * (r[c] + r[c + 32] + r[c + 64] + r[c + 96]);
    }
    __shared__ float red[8][32];
    red[rl][c] = acc;
    __syncthreads();
    if (threadIdx.x < 32) {
        float s = 0.f;
#pragma unroll
        for (int i = 0; i < 8; i++) s += red[i][threadIdx.x];
        atomicAdd(&pooled[g * 32 + threadIdx.x], s);
    }
}

__global__ void mlp_kernel(const float* __restrict__ pooled, const int* __restrict__ gstart,
                           const float* __restrict__ b2,
                           const float* __restrict__ W3, const float* __restrict__ b3,
                           const float* __restrict__ W4, const float* __restrict__ b4,
                           float* __restrict__ out) {
    int g = blockIdx.x;
    int c = threadIdx.x;
    __shared__ float pm[32];
    __shared__ float t[32];
    int cnt = gstart[g + 1] - gstart[g];
    if (c < 32) {
        float m = 0.f;
        if (cnt > 0) m = pooled[g * 32 + c] / (float)cnt + b2[c];
        pm[c] = m;
    }
    __syncthreads();
    if (c < 32) {
        float s = b3[c];
        for (int k = 0; k < 32; k++) s += pm[k] * W3[k * 32 + c];
        t[c] = fmaxf(s, 0.f);
    }
    __syncthreads();
    if (c < 2) {
        float o = b4[c];
        for (int k = 0; k < 32; k++) o += t[k] * W4[k * 2 + c];
        out[g * 2 + c] = o;
    }
}

// ---------------------------------------------------------------------------
extern "C" void kernel_launch(void* const* d_in, const int* in_sizes, int n_in,
                              void* d_out, int out_size, void* d_ws, size_t ws_size,
                              hipStream_t stream) {
    const float* x    = (const float*)d_in[0];
    const int*   eidx = (const int*)d_in[1];
    const float* ea   = (const float*)d_in[2];
    const int*   batch= (const int*)d_in[3];
    const float* W1   = (const float*)d_in[4];
    const float* as1  = (const float*)d_in[5];
    const float* ad1  = (const float*)d_in[6];
    const float* We1  = (const float*)d_in[7];
    const float* ate1 = (const float*)d_in[8];
    const float* b1   = (const float*)d_in[9];
    const float* W2   = (const float*)d_in[10];
    const float* as2  = (const float*)d_in[11];
    const float* ad2  = (const float*)d_in[12];
    const float* We2  = (const float*)d_in[13];
    const float* ate2 = (const float*)d_in[14];
    const float* b2   = (const float*)d_in[15];
    const float* W3   = (const float*)d_in[16];
    const float* b3   = (const float*)d_in[17];
    const float* W4   = (const float*)d_in[18];
    const float* b4   = (const float*)d_in[19];

    const int N_ = in_sizes[0] / 128;
    const int E_ = in_sizes[1] / 2;
    const int EN = E_ + N_;
    const int* srcp = eidx;
    const int* dstp = eidx + E_;
    const int npb = (N_ + BINB - 1) / BINB;
    const int nbk = (EN + BIN_CHUNK - 1) / BIN_CHUNK;

    char* w = (char*)d_ws;
    size_t off = 0;
    auto alloc = [&](size_t bytes) -> void* {
        void* p = w + off;
        off = (off + bytes + 255) & ~(size_t)255;
        return p;
    };
    unsigned short* A   = (unsigned short*)alloc((size_t)N_ * 128 * 2);  // bf16 XW
    unsigned short* Bb16= (unsigned short*)alloc((size_t)N_ * 128 * 2);  // layer1 out bf16
    float* OUT2      = (float*)alloc((size_t)N_ * 128 * 4);              // layer2 out f32
    float* csr_alpha = (float*)alloc((size_t)EN * 16);
    float* aeb2      = (float*)alloc((size_t)EN * 16);
    int2*  csr_se    = (int2*)alloc((size_t)EN * 8);
    int*   row_of    = (int*)alloc((size_t)EN * 4);
    int2*  bin_se    = (int2*)alloc((size_t)EN * 8);
    int*   bin_dst   = (int*)alloc((size_t)EN * 4);
    int*   rowptr    = (int*)alloc((size_t)(N_ + 1) * 4);
    int*   bucket_cnt= (int*)alloc(BINB * 4);
    int*   bucket_off= (int*)alloc(BINB * 4);
    int*   blockbase = (int*)alloc((size_t)nbk * BINB * 4);
    float* a_s       = (float*)alloc((size_t)N_ * 16);
    float* a_d       = (float*)alloc((size_t)N_ * 16);
    float* ea_sums   = (float*)alloc(64);
    float* V1        = (float*)alloc(256);
    float* V2        = (float*)alloc(256);
    float* aes1      = (float*)alloc(16);
    float* aes2      = (float*)alloc(16);
    float* pooled    = (float*)alloc(64 * 32 * 4);
    int*   gstart    = (int*)alloc(65 * 4);

    hipMemsetAsync(bucket_cnt, 0, BINB * 4, stream);
    hipMemsetAsync(ea_sums, 0, 64, stream);
    hipMemsetAsync(pooled, 0, 64 * 32 * 4, stream);

    ea_colsum<<<1024, 256, 0, stream>>>(ea, ea_sums, E_);
    bin_count<<<nbk, 256, 0, stream>>>(dstp, bucket_cnt, blockbase, E_, EN, npb);
    bucket_scan<<<1, BINB, 0, stream>>>(bucket_cnt, bucket_off, rowptr, N_, EN);
    bin_scatter<<<nbk, 256, 0, stream>>>(srcp, dstp, bucket_off, blockbase,
                                         bin_se, bin_dst, E_, EN, npb);
    csr_build<<<BINB, 256, 0, stream>>>(bucket_off, bin_se, bin_dst,
                                        csr_se, row_of, rowptr, N_, EN, npb);
    prep_kernel<<<1, 128, 0, stream>>>(We1, ate1, We2, ate2, ea_sums, 1.0f / (float)E_,
                                       V1, V2, aes1, aes2);
    bounds_kernel<<<1, 128, 0, stream>>>(batch, gstart, N_);

    int gblk = (N_ + 63) / 64;

    // ---- layer 1 ----
    gemm_att_mfma<false><<<gblk, 256, 0, stream>>>(x, W1, as1, ad1, A, a_s, a_d, N_);
    alpha1_fused<<<(EN + 255) / 256, 256, 0, stream>>>(csr_se, row_of, ea, V1, V2,
                                                       aes1, aes2, a_s, a_d,
                                                       csr_alpha, aeb2, E_, EN);
    dst_aggregate<1><<<(N_ + 3) / 4, 256, 0, stream>>>(rowptr, csr_se, csr_alpha,
                                                       nullptr, nullptr,
                                                       (const unsigned int*)A, b1,
                                                       Bb16, N_);

    // ---- layer 2 ----
    gemm_att_mfma<true><<<gblk, 256, 0, stream>>>(Bb16, W2, as2, ad2, A, a_s, a_d, N_);
    dst_aggregate<0><<<(N_ + 3) / 4, 256, 0, stream>>>(rowptr, csr_se, aeb2,
                                                       a_s, a_d,
                                                       (const unsigned int*)A, b2,
                                                       OUT2, N_);
    pool_kernel<<<64 * POOL_SPLITS, 256, 0, stream>>>(OUT2, gstart, pooled);

    // ---- graph MLP ----
    mlp_kernel<<<64, 64, 0, stream>>>(pooled, gstart, b2, W3, b3, W4, b4, (float*)d_out);
}